// Round 20
// baseline (150.855 us; speedup 1.0000x reference)
//
#include <hip/hip_runtime.h>
#include <hip/hip_bf16.h>

// ---- problem dims (compile-time) ----
#define DIM     1024
#define DINNER  2048
#define NSTATE  16
#define DTRANK  64
#define DCONV   4
#define BATCH   2
#define SEQ     1024
#define BL      (BATCH*SEQ)     // 2048 rows
#define XDBLW   96              // DTRANK + 2*NSTATE
#define NCHUNK  32
#define TCHUNK  32              // SEQ / NCHUNK
#define KSLICE  16              // split-K factor for G2
#define G4SK    4               // split-K factor for G4
#define LOG2E   1.44269504088896f
#define LN2     0.69314718055995f

typedef __attribute__((ext_vector_type(4))) float  f32x4;
typedef __attribute__((ext_vector_type(8))) short  bf16x8;
typedef unsigned short ushort_t;

__device__ __forceinline__ ushort_t f2bf(float f) {
    union { float f; unsigned int u; } v; v.f = f;
    unsigned int lsb = (v.u >> 16) & 1u;
    v.u += 0x7fffu + lsb;
    return (ushort_t)(v.u >> 16);
}
__device__ __forceinline__ float bf2f(ushort_t h) {
    union { unsigned u; float f; } v; v.u = ((unsigned)h) << 16; return v.f;
}
// HW-instruction transcendentals (v_exp_f32 = 2^x, v_log_f32 = log2, v_rcp_f32)
__device__ __forceinline__ float hexp2(float x) { return __builtin_amdgcn_exp2f(x); }
__device__ __forceinline__ float hlog2(float x) { return __builtin_amdgcn_logf(x); }
__device__ __forceinline__ float hrcp(float x)  { return __builtin_amdgcn_rcpf(x); }
__device__ __forceinline__ float softplus_fast(float x) {
    float e = hexp2(-fabsf(x) * LOG2E);
    return fmaxf(x, 0.f) + LN2 * hlog2(1.f + e);
}
__device__ __forceinline__ float sigmoid_fast(float x) {
    return hrcp(1.f + hexp2(-x * LOG2E));
}

typedef __attribute__((address_space(1))) unsigned int gu32_t;
typedef __attribute__((address_space(3))) unsigned int lu32_t;
__device__ __forceinline__ void gload_lds16(const ushort_t* g, ushort_t* l) {
    __builtin_amdgcn_global_load_lds((const gu32_t*)(const void*)g,
                                     (lu32_t*)(void*)l, 16, 0, 0);
}

// ================= fused prep: 3 weight transposes + x convert =================
__global__ __launch_bounds__(256) void prep_fused(
    const float* __restrict__ Win,  ushort_t* __restrict__ WtIn,
    const float* __restrict__ Wout, ushort_t* __restrict__ WtOut,
    const float* __restrict__ Wxp,  ushort_t* __restrict__ WtXp,
    const float* __restrict__ x,    ushort_t* __restrict__ xb)
{
    __shared__ float tile[32][33];
    const int tid = threadIdx.x;
    const int tx = tid & 31, ty = tid >> 5;
    const int bid = blockIdx.x;

    const float* src; ushort_t* dst; int R, C, bx, by;
    if (bid < 4096)      { src = Win;  dst = WtIn;  R = 1024; C = 4096; int j = bid;        bx = j % 128; by = j / 128; }
    else if (bid < 6144) { src = Wout; dst = WtOut; R = 2048; C = 1024; int j = bid - 4096; bx = j % 32;  by = j / 32; }
    else if (bid < 6336) { src = Wxp;  dst = WtXp;  R = 2048; C = 96;   int j = bid - 6144; bx = j % 3;   by = j / 3; }
    else {
        int i = ((bid - 6336) * 256 + tid) * 4;
        f32x4 v = *(const f32x4*)(x + i);
        ushort_t r0 = f2bf(v[0]), r1 = f2bf(v[1]), r2 = f2bf(v[2]), r3 = f2bf(v[3]);
        *(uint2*)(xb + i) = make_uint2((unsigned)r0 | ((unsigned)r1 << 16),
                                       (unsigned)r2 | ((unsigned)r3 << 16));
        return;
    }

    const int r0 = by * 32, c0 = bx * 32;
    #pragma unroll
    for (int i = 0; i < 4; ++i)
        tile[ty + i * 8][tx] = src[(size_t)(r0 + ty + i * 8) * C + c0 + tx];
    __syncthreads();
    #pragma unroll
    for (int i = 0; i < 4; ++i)
        dst[(size_t)(c0 + ty + i * 8) * R + r0 + tx] = f2bf(tile[tx][ty + i * 8]);
}

// ======== MFMA GEMM: 64x128 tile, BK=64, dbuf, XOR-swizzled LDS ========
// 1024-block grids -> 3 blocks/CU resident (48 KB LDS). 4 waves (2m x 2n),
// wave = 32x64 output. Counted vmcnt(6) keeps next tile's loads in flight.
__global__ __launch_bounds__(256) void gemm_lds(
    const ushort_t* __restrict__ A,  int lda,   // M x K, M mult of 64
    const ushort_t* __restrict__ Bt, int ldb,   // N x K, N mult of 128
    int K,
    float* __restrict__ Cf, ushort_t* __restrict__ Cb, int ldc)
{
    __shared__ ushort_t As[2][64 * 64];
    __shared__ ushort_t Bs[2][128 * 64];

    const int tid  = threadIdx.x;
    const int m0   = blockIdx.y * 64;
    const int n0   = blockIdx.x * 128;
    const int wid  = tid >> 6;
    const int lane = tid & 63;
    const int wm   = (wid >> 1) * 32;
    const int wn   = (wid & 1) * 64;
    const int lr   = lane & 15;

    int arq[2], agq[2], alo[2];
    #pragma unroll
    for (int q = 0; q < 2; ++q) {
        int c = q * 256 + tid;
        arq[q] = c >> 3;
        agq[q] = ((c & 7) ^ (arq[q] & 7)) * 8;
        alo[q] = (q * 256 + wid * 64) * 8;
    }
    int brq[4], bgq[4], blo[4];
    #pragma unroll
    for (int q = 0; q < 4; ++q) {
        int c = q * 256 + tid;
        brq[q] = c >> 3;
        bgq[q] = ((c & 7) ^ (brq[q] & 7)) * 8;
        blo[q] = (q * 256 + wid * 64) * 8;
    }

    f32x4 acc[2][4];
    #pragma unroll
    for (int m = 0; m < 2; ++m)
        #pragma unroll
        for (int n = 0; n < 4; ++n)
            acc[m][n] = (f32x4){0.f, 0.f, 0.f, 0.f};

    const int nk = K >> 6;

    #pragma unroll
    for (int q = 0; q < 2; ++q)
        gload_lds16(A + (size_t)(m0 + arq[q]) * lda + agq[q], &As[0][alo[q]]);
    #pragma unroll
    for (int q = 0; q < 4; ++q)
        gload_lds16(Bt + (size_t)(n0 + brq[q]) * ldb + bgq[q], &Bs[0][blo[q]]);

    for (int k = 0; k < nk; ++k) {
        const int cur = k & 1;
        if (k + 1 < nk) {
            const int k0 = (k + 1) << 6;
            #pragma unroll
            for (int q = 0; q < 2; ++q)
                gload_lds16(A + (size_t)(m0 + arq[q]) * lda + k0 + agq[q], &As[cur ^ 1][alo[q]]);
            #pragma unroll
            for (int q = 0; q < 4; ++q)
                gload_lds16(Bt + (size_t)(n0 + brq[q]) * ldb + k0 + bgq[q], &Bs[cur ^ 1][blo[q]]);
            asm volatile("s_waitcnt vmcnt(6)" ::: "memory");   // tile k landed; k+1 in flight
        } else {
            asm volatile("s_waitcnt vmcnt(0)" ::: "memory");
        }
        __builtin_amdgcn_sched_barrier(0);
        __builtin_amdgcn_s_barrier();

        #pragma unroll
        for (int kk = 0; kk < 2; ++kk) {
            const int lg = (lane >> 4) + kk * 4;
            const int pc = (lg ^ (lr & 7)) * 8;
            bf16x8 af[2], bfr[4];
            #pragma unroll
            for (int m = 0; m < 2; ++m)
                af[m] = *(const bf16x8*)(&As[cur][(wm + m * 16 + lr) * 64 + pc]);
            #pragma unroll
            for (int n = 0; n < 4; ++n)
                bfr[n] = *(const bf16x8*)(&Bs[cur][(wn + n * 16 + lr) * 64 + pc]);
            #pragma unroll
            for (int m = 0; m < 2; ++m)
                #pragma unroll
                for (int n = 0; n < 4; ++n)
                    acc[m][n] = __builtin_amdgcn_mfma_f32_16x16x32_bf16(af[m], bfr[n], acc[m][n], 0, 0, 0);
        }
        __builtin_amdgcn_s_barrier();
    }

    const int rbase = (lane >> 4) * 4;
    #pragma unroll
    for (int m = 0; m < 2; ++m) {
        #pragma unroll
        for (int n = 0; n < 4; ++n) {
            int col = n0 + wn + n * 16 + lr;
            #pragma unroll
            for (int r = 0; r < 4; ++r) {
                int row = m0 + wm + m * 16 + rbase + r;
                float v = acc[m][n][r];
                if (Cf) Cf[(size_t)row * ldc + col] = v;
                if (Cb) Cb[(size_t)row * ldc + col] = f2bf(v);
            }
        }
    }
}

// ======== G4 split-K variant, same 64x128 swizzled pipeline ========
__global__ __launch_bounds__(256) void gemm_lds_sk(
    const ushort_t* __restrict__ A,  int lda,
    const ushort_t* __restrict__ Bt, int ldb,
    int klen,
    float* __restrict__ Part, int ldc, int mn)   // Part[z][M][ldc]
{
    __shared__ ushort_t As[2][64 * 64];
    __shared__ ushort_t Bs[2][128 * 64];

    const int tid  = threadIdx.x;
    const int m0   = blockIdx.y * 64;
    const int n0   = blockIdx.x * 128;
    const int kb   = blockIdx.z * klen;
    float* Cf = Part + (size_t)blockIdx.z * mn;

    const int wid  = tid >> 6;
    const int lane = tid & 63;
    const int wm   = (wid >> 1) * 32;
    const int wn   = (wid & 1) * 64;
    const int lr   = lane & 15;

    int arq[2], agq[2], alo[2];
    #pragma unroll
    for (int q = 0; q < 2; ++q) {
        int c = q * 256 + tid;
        arq[q] = c >> 3;
        agq[q] = ((c & 7) ^ (arq[q] & 7)) * 8;
        alo[q] = (q * 256 + wid * 64) * 8;
    }
    int brq[4], bgq[4], blo[4];
    #pragma unroll
    for (int q = 0; q < 4; ++q) {
        int c = q * 256 + tid;
        brq[q] = c >> 3;
        bgq[q] = ((c & 7) ^ (brq[q] & 7)) * 8;
        blo[q] = (q * 256 + wid * 64) * 8;
    }

    f32x4 acc[2][4];
    #pragma unroll
    for (int m = 0; m < 2; ++m)
        #pragma unroll
        for (int n = 0; n < 4; ++n)
            acc[m][n] = (f32x4){0.f, 0.f, 0.f, 0.f};

    const int nk = klen >> 6;

    #pragma unroll
    for (int q = 0; q < 2; ++q)
        gload_lds16(A + (size_t)(m0 + arq[q]) * lda + kb + agq[q], &As[0][alo[q]]);
    #pragma unroll
    for (int q = 0; q < 4; ++q)
        gload_lds16(Bt + (size_t)(n0 + brq[q]) * ldb + kb + bgq[q], &Bs[0][blo[q]]);

    for (int k = 0; k < nk; ++k) {
        const int cur = k & 1;
        if (k + 1 < nk) {
            const int k0 = kb + ((k + 1) << 6);
            #pragma unroll
            for (int q = 0; q < 2; ++q)
                gload_lds16(A + (size_t)(m0 + arq[q]) * lda + k0 + agq[q], &As[cur ^ 1][alo[q]]);
            #pragma unroll
            for (int q = 0; q < 4; ++q)
                gload_lds16(Bt + (size_t)(n0 + brq[q]) * ldb + k0 + bgq[q], &Bs[cur ^ 1][blo[q]]);
            asm volatile("s_waitcnt vmcnt(6)" ::: "memory");
        } else {
            asm volatile("s_waitcnt vmcnt(0)" ::: "memory");
        }
        __builtin_amdgcn_sched_barrier(0);
        __builtin_amdgcn_s_barrier();

        #pragma unroll
        for (int kk = 0; kk < 2; ++kk) {
            const int lg = (lane >> 4) + kk * 4;
            const int pc = (lg ^ (lr & 7)) * 8;
            bf16x8 af[2], bfr[4];
            #pragma unroll
            for (int m = 0; m < 2; ++m)
                af[m] = *(const bf16x8*)(&As[cur][(wm + m * 16 + lr) * 64 + pc]);
            #pragma unroll
            for (int n = 0; n < 4; ++n)
                bfr[n] = *(const bf16x8*)(&Bs[cur][(wn + n * 16 + lr) * 64 + pc]);
            #pragma unroll
            for (int m = 0; m < 2; ++m)
                #pragma unroll
                for (int n = 0; n < 4; ++n)
                    acc[m][n] = __builtin_amdgcn_mfma_f32_16x16x32_bf16(af[m], bfr[n], acc[m][n], 0, 0, 0);
        }
        __builtin_amdgcn_s_barrier();
    }

    const int rbase = (lane >> 4) * 4;
    #pragma unroll
    for (int m = 0; m < 2; ++m) {
        #pragma unroll
        for (int n = 0; n < 4; ++n) {
            int col = n0 + wn + n * 16 + lr;
            #pragma unroll
            for (int r = 0; r < 4; ++r) {
                int row = m0 + wm + m * 16 + rbase + r;
                Cf[(size_t)row * ldc + col] = acc[m][n][r];
            }
        }
    }
}

// sum G4SK partials -> f32 out
__global__ __launch_bounds__(256) void g4_reduce(
    const float* __restrict__ Part, float* __restrict__ out)
{
    int i = (blockIdx.x * 256 + threadIdx.x) * 4;
    const size_t mn = (size_t)BL * DIM;
    f32x4 s = *(const f32x4*)(Part + i);
    #pragma unroll
    for (int z = 1; z < G4SK; ++z)
        s += *(const f32x4*)(Part + z * mn + i);
    *(f32x4*)(out + i) = s;
}

// ======== G2 split-K ========
__global__ __launch_bounds__(256) void gemm_n96_splitk(
    const ushort_t* __restrict__ A,
    const ushort_t* __restrict__ Bt,
    float* __restrict__ Ppart)
{
    __shared__ ushort_t As[128 * 40];
    __shared__ ushort_t Bs[96 * 40];

    const int tid   = threadIdx.x;
    const int ks    = blockIdx.x;
    const int m0    = blockIdx.y * 128;
    const int kbase = ks * (DINNER / KSLICE);
    const int wid   = tid >> 6;
    const int lane  = tid & 63;
    const int wm    = wid * 32;
    const int lr    = lane & 15;
    const int lk    = (lane >> 4) * 8;

    f32x4 acc[2][6];
    #pragma unroll
    for (int m = 0; m < 2; ++m)
        #pragma unroll
        for (int n = 0; n < 6; ++n)
            acc[m][n] = (f32x4){0.f, 0.f, 0.f, 0.f};

    for (int k0 = kbase; k0 < kbase + DINNER / KSLICE; k0 += 32) {
        #pragma unroll
        for (int c = 0; c < 2; ++c) {
            int cid = tid + c * 256;
            int row = cid >> 2, ck = (cid & 3) * 8;
            *(uint4*)(&As[row * 40 + ck]) =
                *(const uint4*)(A + (size_t)(m0 + row) * DINNER + k0 + ck);
        }
        {
            int row = tid >> 2, ck = (tid & 3) * 8;
            *(uint4*)(&Bs[row * 40 + ck]) =
                *(const uint4*)(Bt + (size_t)row * DINNER + k0 + ck);
            if (tid < 128) {
                int cid = 256 + tid;
                int row2 = cid >> 2, ck2 = (cid & 3) * 8;
                *(uint4*)(&Bs[row2 * 40 + ck2]) =
                    *(const uint4*)(Bt + (size_t)row2 * DINNER + k0 + ck2);
            }
        }
        __syncthreads();

        bf16x8 af[2], bfr[6];
        #pragma unroll
        for (int m = 0; m < 2; ++m)
            af[m] = *(const bf16x8*)(&As[(wm + m * 16 + lr) * 40 + lk]);
        #pragma unroll
        for (int n = 0; n < 6; ++n)
            bfr[n] = *(const bf16x8*)(&Bs[(n * 16 + lr) * 40 + lk]);

        #pragma unroll
        for (int m = 0; m < 2; ++m)
            #pragma unroll
            for (int n = 0; n < 6; ++n)
                acc[m][n] = __builtin_amdgcn_mfma_f32_16x16x32_bf16(af[m], bfr[n], acc[m][n], 0, 0, 0);
        __syncthreads();
    }

    const int rbase = (lane >> 4) * 4;
    #pragma unroll
    for (int m = 0; m < 2; ++m) {
        #pragma unroll
        for (int n = 0; n < 6; ++n) {
            int col = n * 16 + lr;
            #pragma unroll
            for (int r = 0; r < 4; ++r) {
                int row = m0 + wm + m * 16 + rbase + r;
                Ppart[((size_t)ks * BL + row) * XDBLW + col] = acc[m][n][r];
            }
        }
    }
}

// reduce split-K partials -> xdbl
__global__ __launch_bounds__(256) void g2_reduce(
    const float* __restrict__ Ppart, float* __restrict__ xdbl)
{
    int idx = blockIdx.x * 256 + threadIdx.x;
    int row = idx / 24, cg = (idx % 24) * 4;
    f32x4 s = (f32x4){0.f, 0.f, 0.f, 0.f};
    #pragma unroll
    for (int ks = 0; ks < KSLICE; ++ks)
        s += *(const f32x4*)(Ppart + ((size_t)ks * BL + row) * XDBLW + cg);
    *(f32x4*)(xdbl + (size_t)row * XDBLW + cg) = s;
}

// ======== delta_v6: packed layout + fast softplus ========
__global__ __launch_bounds__(256, 4) void delta_v6(
    const float* __restrict__ xdbl,
    const float* __restrict__ Wdt,
    const float* __restrict__ dtb,
    ushort_t* __restrict__ delta_bf)
{
    __shared__ float WS[64][256];
    __shared__ float dS[32][64];
    const int tid  = threadIdx.x;
    const int d0   = (blockIdx.x & 7) * 256;
    const int row0 = (blockIdx.x >> 3) * 32;

    #pragma unroll
    for (int i = 0; i < 16; ++i) {
        int c = i * 256 + tid;
        int k = c >> 6, co = (c & 63) * 4;
        *(f32x4*)&WS[k][co] = *(const f32x4*)(Wdt + (size_t)k * DINNER + d0 + co);
    }
    #pragma unroll
    for (int i = 0; i < 2; ++i) {
        int c = i * 256 + tid;
        int r = c >> 4, co = (c & 15) * 4;
        *(f32x4*)&dS[r][co] = *(const f32x4*)(xdbl + (size_t)(row0 + r) * XDBLW + co);
    }
    __syncthreads();

    const int w    = tid >> 6;
    const int lane = tid & 63;
    const int dd   = lane * 4;

    f32x4 acc[8];
    {
        f32x4 bb = *(const f32x4*)(dtb + d0 + dd);
        #pragma unroll
        for (int r = 0; r < 8; ++r) acc[r] = bb;
    }

    for (int kq = 0; kq < 16; ++kq) {
        f32x4 dv[8];
        #pragma unroll
        for (int r = 0; r < 8; ++r)
            dv[r] = *(const f32x4*)&dS[w * 8 + r][kq * 4];
        #pragma unroll
        for (int kk = 0; kk < 4; ++kk) {
            f32x4 wv = *(const f32x4*)&WS[kq * 4 + kk][dd];
            #pragma unroll
            for (int r = 0; r < 8; ++r) {
                float dk = dv[r][kk];
                acc[r][0] = fmaf(dk, wv[0], acc[r][0]);
                acc[r][1] = fmaf(dk, wv[1], acc[r][1]);
                acc[r][2] = fmaf(dk, wv[2], acc[r][2]);
                acc[r][3] = fmaf(dk, wv[3], acc[r][3]);
            }
        }
    }

    #pragma unroll
    for (int r = 0; r < 8; ++r) {
        const size_t rowb = (size_t)(row0 + w * 8 + r) * DINNER + d0;
        f32x4 v = acc[r];
        ushort_t o[4];
        #pragma unroll
        for (int j = 0; j < 4; ++j)
            o[j] = f2bf(softplus_fast(v[j]));
        *(uint2*)(delta_bf + rowb + dd) = make_uint2(
            (unsigned)o[0] | ((unsigned)o[1] << 16), (unsigned)o[2] | ((unsigned)o[3] << 16));
    }
}

// ---------------- conv(4) + bias + SiLU, vectorized (8 d per thread) ----------------
__global__ __launch_bounds__(256) void conv_silu(
    const ushort_t* __restrict__ xrb,   // BL x 4096 bf16 (xp = cols [0,2048))
    const float* __restrict__ convw,
    const float* __restrict__ convb,
    ushort_t* __restrict__ hb)          // BL x 2048 bf16
{
    const int bt = blockIdx.x;
    const int t  = bt & (SEQ - 1);
    const int d0 = threadIdx.x * 8;

    bf16x8 xv[DCONV];
    #pragma unroll
    for (int j = 0; j < DCONV; ++j) {
        int tt = t + j - (DCONV - 1);
        if (tt >= 0)
            xv[j] = *(const bf16x8*)(xrb + (size_t)(bt + j - (DCONV - 1)) * 4096 + d0);
        else
            xv[j] = (bf16x8){0,0,0,0,0,0,0,0};
    }

    ushort_t o[8];
    #pragma unroll
    for (int dd = 0; dd < 8; ++dd) {
        f32x4 w = *(const f32x4*)(convw + (size_t)(d0 + dd) * DCONV);
        float acc = convb[d0 + dd];
        #pragma unroll
        for (int j = 0; j < DCONV; ++j)
            acc = fmaf(w[j], bf2f((ushort_t)xv[j][dd]), acc);
        o[dd] = f2bf(acc * sigmoid_fast(acc));
    }
    uint4 pk;
    pk.x = (unsigned)o[0] | ((unsigned)o[1] << 16);
    pk.y = (unsigned)o[2] | ((unsigned)o[3] << 16);
    pk.z = (unsigned)o[4] | ((unsigned)o[5] << 16);
    pk.w = (unsigned)o[6] | ((unsigned)o[7] << 16);
    *(uint4*)(hb + (size_t)bt * DINNER + d0) = pk;
}

// ================= chunked parallel selective scan =================
__global__ __launch_bounds__(256) void scan_p1(
    const ushort_t* __restrict__ delta_bf,
    const ushort_t* __restrict__ hb,
    const float* __restrict__ xdbl,
    const float* __restrict__ Alog,
    float* __restrict__ Pbuf,
    float* __restrict__ Sbuf)
{
    const int d  = (blockIdx.x & 7) * 256 + threadIdx.x;
    const int bc = blockIdx.x >> 3;
    const int b  = bc >> 5;
    const int c  = bc & (NCHUNK - 1);
    const int t0 = c * TCHUNK;

    float A[NSTATE];
    #pragma unroll
    for (int q = 0; q < 4; ++q) {
        f32x4 al = *(const f32x4*)(Alog + (size_t)d * NSTATE + q * 4);
        #pragma unroll
        for (int j = 0; j < 4; ++j)
            A[q * 4 + j] = -hexp2(al[j] * LOG2E) * LOG2E;
    }

    float s[NSTATE], pp[NSTATE];
    #pragma unroll
    for (int n = 0; n < NSTATE; ++n) { s[n] = 0.f; pp[n] = 1.f; }

    for (int tt = 0; tt < TCHUNK; ++tt) {
        const size_t row = (size_t)(b * SEQ + t0 + tt);
        float dl = bf2f(delta_bf[row * DINNER + d]);
        float hv = bf2f(hb[row * DINNER + d]);
        float dlh = dl * hv;
        float Bv[NSTATE];
        #pragma unroll
        for (int q = 0; q < 4; ++q) {
            f32x4 bv = *(const f32x4*)(xdbl + row * XDBLW + DTRANK + q * 4);
            #pragma unroll
            for (int j = 0; j < 4; ++j) Bv[q * 4 + j] = bv[j];
        }
        #pragma unroll
        for (int n = 0; n < NSTATE; ++n) {
            float a = hexp2(dl * A[n]);
            s[n]  = fmaf(a, s[n], dlh * Bv[n]);
            pp[n] *= a;
        }
    }

    const size_t o = (((size_t)b * NCHUNK + c) * DINNER + d) * NSTATE;
    #pragma unroll
    for (int q = 0; q < 4; ++q) {
        *(f32x4*)(Sbuf + o + q * 4) = (f32x4){s[q*4+0], s[q*4+1], s[q*4+2], s[q*4+3]};
        *(f32x4*)(Pbuf + o + q * 4) = (f32x4){pp[q*4+0], pp[q*4+1], pp[q*4+2], pp[q*4+3]};
    }
}

// register-batched carry: load all chunk summaries (independent), chain in-reg, store
__global__ __launch_bounds__(256) void scan_p2(
    const float* __restrict__ Pbuf, float* __restrict__ Sbuf)
{
    const int tid = blockIdx.x * 256 + threadIdx.x;
    const int n = tid & 15;
    const int d = (tid >> 4) & (DINNER - 1);
    const int b = tid >> 15;
    const size_t stride = (size_t)DINNER * NSTATE;
    const size_t base = ((size_t)b * NCHUNK * DINNER + d) * NSTATE + n;

    float S[NCHUNK], P[NCHUNK];
    #pragma unroll
    for (int c = 0; c < NCHUNK; ++c) {
        S[c] = Sbuf[base + c * stride];
        P[c] = Pbuf[base + c * stride];
    }
    float cin = 0.f;
    float O[NCHUNK];
    #pragma unroll
    for (int c = 0; c < NCHUNK; ++c) {
        O[c] = cin;
        cin = fmaf(P[c], cin, S[c]);
    }
    #pragma unroll
    for (int c = 0; c < NCHUNK; ++c)
        Sbuf[base + c * stride] = O[c];
}

__global__ __launch_bounds__(256) void scan_p3(
    const ushort_t* __restrict__ delta_bf,
    const ushort_t* __restrict__ hb,
    const float* __restrict__ xdbl,
    const ushort_t* __restrict__ xrb,
    const float* __restrict__ Alog,
    const float* __restrict__ Dp,
    const float* __restrict__ Sbuf,
    ushort_t* __restrict__ yb)
{
    const int d  = (blockIdx.x & 7) * 256 + threadIdx.x;
    const int bc = blockIdx.x >> 3;
    const int b  = bc >> 5;
    const int c  = bc & (NCHUNK - 1);
    const int t0 = c * TCHUNK;

    float A[NSTATE];
    #pragma unroll
    for (int q = 0; q < 4; ++q) {
        f32x4 al = *(const f32x4*)(Alog + (size_t)d * NSTATE + q * 4);
        #pragma unroll
        for (int j = 0; j < 4; ++j)
            A[q * 4 + j] = -hexp2(al[j] * LOG2E) * LOG2E;
    }
    const float Dd = Dp[d];

    float s[NSTATE];
    const size_t o = (((size_t)b * NCHUNK + c) * DINNER + d) * NSTATE;
    #pragma unroll
    for (int q = 0; q < 4; ++q) {
        f32x4 sv = *(const f32x4*)(Sbuf + o + q * 4);
        #pragma unroll
        for (int j = 0; j < 4; ++j) s[q * 4 + j] = sv[j];
    }

    for (int tt = 0; tt < TCHUNK; ++tt) {
        const size_t row = (size_t)(b * SEQ + t0 + tt);
        float dl = bf2f(delta_bf[row * DINNER + d]);
        float hv = bf2f(hb[row * DINNER + d]);
        float rv = bf2f(xrb[row * 4096 + DINNER + d]);
        float dlh = dl * hv;
        float Bv[NSTATE], Cv[NSTATE];
        #pragma unroll
        for (int q = 0; q < 4; ++q) {
            f32x4 bv = *(const f32x4*)(xdbl + row * XDBLW + DTRANK + q * 4);
            f32x4 cv = *(const f32x4*)(xdbl + row * XDBLW + DTRANK + NSTATE + q * 4);
            #pragma unroll
            for (int j = 0; j < 4; ++j) { Bv[q*4+j] = bv[j]; Cv[q*4+j] = cv[j]; }
        }
        float y = 0.f;
        #pragma unroll
        for (int n = 0; n < NSTATE; ++n) {
            float a = hexp2(dl * A[n]);
            s[n] = fmaf(a, s[n], dlh * Bv[n]);
            y = fmaf(s[n], Cv[n], y);
        }
        y = fmaf(hv, Dd, y);
        y = y * rv * sigmoid_fast(rv);
        yb[row * DINNER + d] = f2bf(y);
    }
}

extern "C" void kernel_launch(void* const* d_in, const int* in_sizes, int n_in,
                              void* d_out, int out_size, void* d_ws, size_t ws_size,
                              hipStream_t stream)
{
    const float* x     = (const float*)d_in[0];
    const float* Win   = (const float*)d_in[1];
    const float* convw = (const float*)d_in[2];
    const float* convb = (const float*)d_in[3];
    const float* Wxp   = (const float*)d_in[4];
    const float* Wdt   = (const float*)d_in[5];
    const float* dtb   = (const float*)d_in[6];
    const float* Alog  = (const float*)d_in[7];
    const float* Dp    = (const float*)d_in[8];
    const float* Wout  = (const float*)d_in[9];
    float* out = (float*)d_out;

    char* base = (char*)d_ws; size_t off = 0;
    auto alloc = [&](size_t bytes) -> char* {
        char* q = base + off;
        off = (off + bytes + 255) & ~(size_t)255;
        return q;
    };
    ushort_t* WtIn   = (ushort_t*)alloc((size_t)4096 * 1024 * 2);
    ushort_t* WtOut  = (ushort_t*)alloc((size_t)1024 * 2048 * 2);
    ushort_t* WtXp   = (ushort_t*)alloc((size_t)96   * 2048 * 2);
    ushort_t* xb     = (ushort_t*)alloc((size_t)BL * DIM * 2);
    ushort_t* xrb    = (ushort_t*)alloc((size_t)BL * 4096 * 2);
    ushort_t* hb     = (ushort_t*)alloc((size_t)BL * DINNER * 2);
    float*    xdbl   = (float*)   alloc((size_t)BL * XDBLW * 4);
    ushort_t* dltbf  = (ushort_t*)alloc((size_t)BL * DINNER * 2);
    ushort_t* yb     = (ushort_t*)alloc((size_t)BL * DINNER * 2);
    float*    Pbuf   = (float*)   alloc((size_t)BATCH * NCHUNK * DINNER * NSTATE * 4);
    float*    Sbuf   = (float*)   alloc((size_t)BATCH * NCHUNK * DINNER * NSTATE * 4);
    float*    Ppart  = (float*)   alloc((size_t)KSLICE * BL * XDBLW * 4);
    float*    G4part = (float*)   alloc((size_t)G4SK * BL * DIM * 4);   // 32 MB
    (void)ws_size;

    prep_fused<<<dim3(8384), 256, 0, stream>>>(Win, WtIn, Wout, WtOut, Wxp, WtXp, x, xb);

    // G1: xr = x @ in_proj_w (2048 x 4096, K=1024) -> bf16; 64x128 tiles, 1024 blocks
    gemm_lds<<<dim3(4096/128, BL/64), 256, 0, stream>>>(
        xb, DIM, WtIn, DIM, DIM, nullptr, xrb, 2*DINNER);

    conv_silu<<<dim3(BL), 256, 0, stream>>>(xrb, convw, convb, hb);

    gemm_n96_splitk<<<dim3(KSLICE, BL/128), 256, 0, stream>>>(hb, WtXp, Ppart);
    g2_reduce<<<dim3(BL * 24 / 256), 256, 0, stream>>>(Ppart, xdbl);

    delta_v6<<<dim3(8 * (BL / 32)), 256, 0, stream>>>(xdbl, Wdt, dtb, dltbf);

    scan_p1<<<dim3(8 * BATCH * NCHUNK), 256, 0, stream>>>(dltbf, hb, xdbl, Alog, Pbuf, Sbuf);
    scan_p2<<<dim3(BATCH * DINNER * NSTATE / 256), 256, 0, stream>>>(Pbuf, Sbuf);
    scan_p3<<<dim3(8 * BATCH * NCHUNK), 256, 0, stream>>>(dltbf, hb, xdbl, xrb, Alog, Dp, Sbuf, yb);

    // G4: out = y @ out_proj_w (2048 x 1024, K=2048) via split-K=4; 64x128 tiles
    gemm_lds_sk<<<dim3(DIM/128, BL/64, G4SK), 256, 0, stream>>>(
        yb, DINNER, WtOut, DINNER, DINNER/G4SK, G4part, DIM, BL*DIM);
    g4_reduce<<<dim3(BL*DIM/4/256), 256, 0, stream>>>(G4part, out);
}

// Round 21
// 140.349 us; speedup vs baseline: 1.0749x; 1.0749x over previous
//
#include <hip/hip_runtime.h>
#include <hip/hip_bf16.h>

// ---- problem dims (compile-time) ----
#define DIM     1024
#define DINNER  2048
#define NSTATE  16
#define DTRANK  64
#define DCONV   4
#define BATCH   2
#define SEQ     1024
#define BL      (BATCH*SEQ)     // 2048 rows
#define XDBLW   96              // DTRANK + 2*NSTATE
#define NCHUNK  32
#define TCHUNK  32              // SEQ / NCHUNK
#define KSLICE  16              // split-K factor for G2
#define G4SK    4               // split-K factor for G4
#define LOG2E   1.44269504088896f
#define LN2     0.69314718055995f

typedef __attribute__((ext_vector_type(4))) float  f32x4;
typedef __attribute__((ext_vector_type(8))) short  bf16x8;
typedef unsigned short ushort_t;

__device__ __forceinline__ ushort_t f2bf(float f) {
    union { float f; unsigned int u; } v; v.f = f;
    unsigned int lsb = (v.u >> 16) & 1u;
    v.u += 0x7fffu + lsb;
    return (ushort_t)(v.u >> 16);
}
__device__ __forceinline__ float bf2f(ushort_t h) {
    union { unsigned u; float f; } v; v.u = ((unsigned)h) << 16; return v.f;
}
// HW-instruction transcendentals (v_exp_f32 = 2^x, v_log_f32 = log2, v_rcp_f32)
__device__ __forceinline__ float hexp2(float x) { return __builtin_amdgcn_exp2f(x); }
__device__ __forceinline__ float hlog2(float x) { return __builtin_amdgcn_logf(x); }
__device__ __forceinline__ float hrcp(float x)  { return __builtin_amdgcn_rcpf(x); }
__device__ __forceinline__ float softplus_fast(float x) {
    float e = hexp2(-fabsf(x) * LOG2E);
    return fmaxf(x, 0.f) + LN2 * hlog2(1.f + e);
}
__device__ __forceinline__ float sigmoid_fast(float x) {
    return hrcp(1.f + hexp2(-x * LOG2E));
}

typedef __attribute__((address_space(1))) unsigned int gu32_t;
typedef __attribute__((address_space(3))) unsigned int lu32_t;
__device__ __forceinline__ void gload_lds16(const ushort_t* g, ushort_t* l) {
    __builtin_amdgcn_global_load_lds((const gu32_t*)(const void*)g,
                                     (lu32_t*)(void*)l, 16, 0, 0);
}

// ================= fused prep: 3 weight transposes + x convert =================
__global__ __launch_bounds__(256) void prep_fused(
    const float* __restrict__ Win,  ushort_t* __restrict__ WtIn,
    const float* __restrict__ Wout, ushort_t* __restrict__ WtOut,
    const float* __restrict__ Wxp,  ushort_t* __restrict__ WtXp,
    const float* __restrict__ x,    ushort_t* __restrict__ xb)
{
    __shared__ float tile[32][33];
    const int tid = threadIdx.x;
    const int tx = tid & 31, ty = tid >> 5;
    const int bid = blockIdx.x;

    const float* src; ushort_t* dst; int R, C, bx, by;
    if (bid < 4096)      { src = Win;  dst = WtIn;  R = 1024; C = 4096; int j = bid;        bx = j % 128; by = j / 128; }
    else if (bid < 6144) { src = Wout; dst = WtOut; R = 2048; C = 1024; int j = bid - 4096; bx = j % 32;  by = j / 32; }
    else if (bid < 6336) { src = Wxp;  dst = WtXp;  R = 2048; C = 96;   int j = bid - 6144; bx = j % 3;   by = j / 3; }
    else {
        int i = ((bid - 6336) * 256 + tid) * 4;
        f32x4 v = *(const f32x4*)(x + i);
        ushort_t r0 = f2bf(v[0]), r1 = f2bf(v[1]), r2 = f2bf(v[2]), r3 = f2bf(v[3]);
        *(uint2*)(xb + i) = make_uint2((unsigned)r0 | ((unsigned)r1 << 16),
                                       (unsigned)r2 | ((unsigned)r3 << 16));
        return;
    }

    const int r0 = by * 32, c0 = bx * 32;
    #pragma unroll
    for (int i = 0; i < 4; ++i)
        tile[ty + i * 8][tx] = src[(size_t)(r0 + ty + i * 8) * C + c0 + tx];
    __syncthreads();
    #pragma unroll
    for (int i = 0; i < 4; ++i)
        dst[(size_t)(c0 + ty + i * 8) * R + r0 + tx] = f2bf(tile[tx][ty + i * 8]);
}

// ======== MFMA GEMM: 128x128 tile, BK=64, dbuf, XOR-swizzled LDS ========
// Proven best config (R18/R19): counted vmcnt(8), conflict-free ds_read.
__global__ __launch_bounds__(256) void gemm_lds(
    const ushort_t* __restrict__ A,  int lda,
    const ushort_t* __restrict__ Bt, int ldb,
    int K,
    float* __restrict__ Cf, ushort_t* __restrict__ Cb, int ldc)
{
    __shared__ ushort_t As[2][128 * 64];
    __shared__ ushort_t Bs[2][128 * 64];

    const int tid  = threadIdx.x;
    const int m0   = blockIdx.y * 128;
    const int n0   = blockIdx.x * 128;
    const int wid  = tid >> 6;
    const int lane = tid & 63;
    const int wm   = (wid >> 1) * 64;
    const int wn   = (wid & 1) * 64;
    const int lr   = lane & 15;

    int rq[4], gq[4], lo[4];
    #pragma unroll
    for (int q = 0; q < 4; ++q) {
        int c = q * 256 + tid;
        rq[q] = c >> 3;
        gq[q] = ((c & 7) ^ (rq[q] & 7)) * 8;
        lo[q] = (q * 256 + wid * 64) * 8;
    }

    f32x4 acc[4][4];
    #pragma unroll
    for (int m = 0; m < 4; ++m)
        #pragma unroll
        for (int n = 0; n < 4; ++n)
            acc[m][n] = (f32x4){0.f, 0.f, 0.f, 0.f};

    const int nk = K >> 6;

    #pragma unroll
    for (int q = 0; q < 4; ++q) {
        gload_lds16(A  + (size_t)(m0 + rq[q]) * lda + gq[q], &As[0][lo[q]]);
        gload_lds16(Bt + (size_t)(n0 + rq[q]) * ldb + gq[q], &Bs[0][lo[q]]);
    }

    for (int k = 0; k < nk; ++k) {
        const int cur = k & 1;
        if (k + 1 < nk) {
            const int k0 = (k + 1) << 6;
            #pragma unroll
            for (int q = 0; q < 4; ++q) {
                gload_lds16(A  + (size_t)(m0 + rq[q]) * lda + k0 + gq[q], &As[cur ^ 1][lo[q]]);
                gload_lds16(Bt + (size_t)(n0 + rq[q]) * ldb + k0 + gq[q], &Bs[cur ^ 1][lo[q]]);
            }
            asm volatile("s_waitcnt vmcnt(8)" ::: "memory");
        } else {
            asm volatile("s_waitcnt vmcnt(0)" ::: "memory");
        }
        __builtin_amdgcn_sched_barrier(0);
        __builtin_amdgcn_s_barrier();

        #pragma unroll
        for (int kk = 0; kk < 2; ++kk) {
            const int lg = (lane >> 4) + kk * 4;
            const int pc = (lg ^ (lr & 7)) * 8;
            bf16x8 af[4], bfr[4];
            #pragma unroll
            for (int m = 0; m < 4; ++m)
                af[m] = *(const bf16x8*)(&As[cur][(wm + m * 16 + lr) * 64 + pc]);
            #pragma unroll
            for (int n = 0; n < 4; ++n)
                bfr[n] = *(const bf16x8*)(&Bs[cur][(wn + n * 16 + lr) * 64 + pc]);
            #pragma unroll
            for (int m = 0; m < 4; ++m)
                #pragma unroll
                for (int n = 0; n < 4; ++n)
                    acc[m][n] = __builtin_amdgcn_mfma_f32_16x16x32_bf16(af[m], bfr[n], acc[m][n], 0, 0, 0);
        }
        __builtin_amdgcn_s_barrier();
    }

    const int rbase = (lane >> 4) * 4;
    #pragma unroll
    for (int m = 0; m < 4; ++m) {
        #pragma unroll
        for (int n = 0; n < 4; ++n) {
            int col = n0 + wn + n * 16 + lr;
            #pragma unroll
            for (int r = 0; r < 4; ++r) {
                int row = m0 + wm + m * 16 + rbase + r;
                float v = acc[m][n][r];
                if (Cf) Cf[(size_t)row * ldc + col] = v;
                if (Cb) Cb[(size_t)row * ldc + col] = f2bf(v);
            }
        }
    }
}

// ======== G4 split-K variant, same 128x128 BK=64 swizzled pipeline ========
__global__ __launch_bounds__(256) void gemm_lds_sk(
    const ushort_t* __restrict__ A,  int lda,
    const ushort_t* __restrict__ Bt, int ldb,
    int klen,
    float* __restrict__ Part, int ldc, int mn)   // Part[z][M][ldc]
{
    __shared__ ushort_t As[2][128 * 64];
    __shared__ ushort_t Bs[2][128 * 64];

    const int tid  = threadIdx.x;
    const int m0   = blockIdx.y * 128;
    const int n0   = blockIdx.x * 128;
    const int kb   = blockIdx.z * klen;
    float* Cf = Part + (size_t)blockIdx.z * mn;

    const int wid  = tid >> 6;
    const int lane = tid & 63;
    const int wm   = (wid >> 1) * 64;
    const int wn   = (wid & 1) * 64;
    const int lr   = lane & 15;

    int rq[4], gq[4], lo[4];
    #pragma unroll
    for (int q = 0; q < 4; ++q) {
        int c = q * 256 + tid;
        rq[q] = c >> 3;
        gq[q] = ((c & 7) ^ (rq[q] & 7)) * 8;
        lo[q] = (q * 256 + wid * 64) * 8;
    }

    f32x4 acc[4][4];
    #pragma unroll
    for (int m = 0; m < 4; ++m)
        #pragma unroll
        for (int n = 0; n < 4; ++n)
            acc[m][n] = (f32x4){0.f, 0.f, 0.f, 0.f};

    const int nk = klen >> 6;

    #pragma unroll
    for (int q = 0; q < 4; ++q) {
        gload_lds16(A  + (size_t)(m0 + rq[q]) * lda + kb + gq[q], &As[0][lo[q]]);
        gload_lds16(Bt + (size_t)(n0 + rq[q]) * ldb + kb + gq[q], &Bs[0][lo[q]]);
    }

    for (int k = 0; k < nk; ++k) {
        const int cur = k & 1;
        if (k + 1 < nk) {
            const int k0 = kb + ((k + 1) << 6);
            #pragma unroll
            for (int q = 0; q < 4; ++q) {
                gload_lds16(A  + (size_t)(m0 + rq[q]) * lda + k0 + gq[q], &As[cur ^ 1][lo[q]]);
                gload_lds16(Bt + (size_t)(n0 + rq[q]) * ldb + k0 + gq[q], &Bs[cur ^ 1][lo[q]]);
            }
            asm volatile("s_waitcnt vmcnt(8)" ::: "memory");
        } else {
            asm volatile("s_waitcnt vmcnt(0)" ::: "memory");
        }
        __builtin_amdgcn_sched_barrier(0);
        __builtin_amdgcn_s_barrier();

        #pragma unroll
        for (int kk = 0; kk < 2; ++kk) {
            const int lg = (lane >> 4) + kk * 4;
            const int pc = (lg ^ (lr & 7)) * 8;
            bf16x8 af[4], bfr[4];
            #pragma unroll
            for (int m = 0; m < 4; ++m)
                af[m] = *(const bf16x8*)(&As[cur][(wm + m * 16 + lr) * 64 + pc]);
            #pragma unroll
            for (int n = 0; n < 4; ++n)
                bfr[n] = *(const bf16x8*)(&Bs[cur][(wn + n * 16 + lr) * 64 + pc]);
            #pragma unroll
            for (int m = 0; m < 4; ++m)
                #pragma unroll
                for (int n = 0; n < 4; ++n)
                    acc[m][n] = __builtin_amdgcn_mfma_f32_16x16x32_bf16(af[m], bfr[n], acc[m][n], 0, 0, 0);
        }
        __builtin_amdgcn_s_barrier();
    }

    const int rbase = (lane >> 4) * 4;
    #pragma unroll
    for (int m = 0; m < 4; ++m) {
        #pragma unroll
        for (int n = 0; n < 4; ++n) {
            int col = n0 + wn + n * 16 + lr;
            #pragma unroll
            for (int r = 0; r < 4; ++r) {
                int row = m0 + wm + m * 16 + rbase + r;
                Cf[(size_t)row * ldc + col] = acc[m][n][r];
            }
        }
    }
}

// sum G4SK partials -> f32 out
__global__ __launch_bounds__(256) void g4_reduce(
    const float* __restrict__ Part, float* __restrict__ out)
{
    int i = (blockIdx.x * 256 + threadIdx.x) * 4;
    const size_t mn = (size_t)BL * DIM;
    f32x4 s = *(const f32x4*)(Part + i);
    #pragma unroll
    for (int z = 1; z < G4SK; ++z)
        s += *(const f32x4*)(Part + z * mn + i);
    *(f32x4*)(out + i) = s;
}

// ======== G2 split-K ========
__global__ __launch_bounds__(256) void gemm_n96_splitk(
    const ushort_t* __restrict__ A,
    const ushort_t* __restrict__ Bt,
    float* __restrict__ Ppart)
{
    __shared__ ushort_t As[128 * 40];
    __shared__ ushort_t Bs[96 * 40];

    const int tid   = threadIdx.x;
    const int ks    = blockIdx.x;
    const int m0    = blockIdx.y * 128;
    const int kbase = ks * (DINNER / KSLICE);
    const int wid   = tid >> 6;
    const int lane  = tid & 63;
    const int wm    = wid * 32;
    const int lr    = lane & 15;
    const int lk    = (lane >> 4) * 8;

    f32x4 acc[2][6];
    #pragma unroll
    for (int m = 0; m < 2; ++m)
        #pragma unroll
        for (int n = 0; n < 6; ++n)
            acc[m][n] = (f32x4){0.f, 0.f, 0.f, 0.f};

    for (int k0 = kbase; k0 < kbase + DINNER / KSLICE; k0 += 32) {
        #pragma unroll
        for (int c = 0; c < 2; ++c) {
            int cid = tid + c * 256;
            int row = cid >> 2, ck = (cid & 3) * 8;
            *(uint4*)(&As[row * 40 + ck]) =
                *(const uint4*)(A + (size_t)(m0 + row) * DINNER + k0 + ck);
        }
        {
            int row = tid >> 2, ck = (tid & 3) * 8;
            *(uint4*)(&Bs[row * 40 + ck]) =
                *(const uint4*)(Bt + (size_t)row * DINNER + k0 + ck);
            if (tid < 128) {
                int cid = 256 + tid;
                int row2 = cid >> 2, ck2 = (cid & 3) * 8;
                *(uint4*)(&Bs[row2 * 40 + ck2]) =
                    *(const uint4*)(Bt + (size_t)row2 * DINNER + k0 + ck2);
            }
        }
        __syncthreads();

        bf16x8 af[2], bfr[6];
        #pragma unroll
        for (int m = 0; m < 2; ++m)
            af[m] = *(const bf16x8*)(&As[(wm + m * 16 + lr) * 40 + lk]);
        #pragma unroll
        for (int n = 0; n < 6; ++n)
            bfr[n] = *(const bf16x8*)(&Bs[(n * 16 + lr) * 40 + lk]);

        #pragma unroll
        for (int m = 0; m < 2; ++m)
            #pragma unroll
            for (int n = 0; n < 6; ++n)
                acc[m][n] = __builtin_amdgcn_mfma_f32_16x16x32_bf16(af[m], bfr[n], acc[m][n], 0, 0, 0);
        __syncthreads();
    }

    const int rbase = (lane >> 4) * 4;
    #pragma unroll
    for (int m = 0; m < 2; ++m) {
        #pragma unroll
        for (int n = 0; n < 6; ++n) {
            int col = n * 16 + lr;
            #pragma unroll
            for (int r = 0; r < 4; ++r) {
                int row = m0 + wm + m * 16 + rbase + r;
                Ppart[((size_t)ks * BL + row) * XDBLW + col] = acc[m][n][r];
            }
        }
    }
}

// reduce split-K partials -> xdbl
__global__ __launch_bounds__(256) void g2_reduce(
    const float* __restrict__ Ppart, float* __restrict__ xdbl)
{
    int idx = blockIdx.x * 256 + threadIdx.x;
    int row = idx / 24, cg = (idx % 24) * 4;
    f32x4 s = (f32x4){0.f, 0.f, 0.f, 0.f};
    #pragma unroll
    for (int ks = 0; ks < KSLICE; ++ks)
        s += *(const f32x4*)(Ppart + ((size_t)ks * BL + row) * XDBLW + cg);
    *(f32x4*)(xdbl + (size_t)row * XDBLW + cg) = s;
}

// ======== delta_v6: packed layout + fast softplus ========
__global__ __launch_bounds__(256, 4) void delta_v6(
    const float* __restrict__ xdbl,
    const float* __restrict__ Wdt,
    const float* __restrict__ dtb,
    ushort_t* __restrict__ delta_bf)
{
    __shared__ float WS[64][256];
    __shared__ float dS[32][64];
    const int tid  = threadIdx.x;
    const int d0   = (blockIdx.x & 7) * 256;
    const int row0 = (blockIdx.x >> 3) * 32;

    #pragma unroll
    for (int i = 0; i < 16; ++i) {
        int c = i * 256 + tid;
        int k = c >> 6, co = (c & 63) * 4;
        *(f32x4*)&WS[k][co] = *(const f32x4*)(Wdt + (size_t)k * DINNER + d0 + co);
    }
    #pragma unroll
    for (int i = 0; i < 2; ++i) {
        int c = i * 256 + tid;
        int r = c >> 4, co = (c & 15) * 4;
        *(f32x4*)&dS[r][co] = *(const f32x4*)(xdbl + (size_t)(row0 + r) * XDBLW + co);
    }
    __syncthreads();

    const int w    = tid >> 6;
    const int lane = tid & 63;
    const int dd   = lane * 4;

    f32x4 acc[8];
    {
        f32x4 bb = *(const f32x4*)(dtb + d0 + dd);
        #pragma unroll
        for (int r = 0; r < 8; ++r) acc[r] = bb;
    }

    for (int kq = 0; kq < 16; ++kq) {
        f32x4 dv[8];
        #pragma unroll
        for (int r = 0; r < 8; ++r)
            dv[r] = *(const f32x4*)&dS[w * 8 + r][kq * 4];
        #pragma unroll
        for (int kk = 0; kk < 4; ++kk) {
            f32x4 wv = *(const f32x4*)&WS[kq * 4 + kk][dd];
            #pragma unroll
            for (int r = 0; r < 8; ++r) {
                float dk = dv[r][kk];
                acc[r][0] = fmaf(dk, wv[0], acc[r][0]);
                acc[r][1] = fmaf(dk, wv[1], acc[r][1]);
                acc[r][2] = fmaf(dk, wv[2], acc[r][2]);
                acc[r][3] = fmaf(dk, wv[3], acc[r][3]);
            }
        }
    }

    #pragma unroll
    for (int r = 0; r < 8; ++r) {
        const size_t rowb = (size_t)(row0 + w * 8 + r) * DINNER + d0;
        f32x4 v = acc[r];
        ushort_t o[4];
        #pragma unroll
        for (int j = 0; j < 4; ++j)
            o[j] = f2bf(softplus_fast(v[j]));
        *(uint2*)(delta_bf + rowb + dd) = make_uint2(
            (unsigned)o[0] | ((unsigned)o[1] << 16), (unsigned)o[2] | ((unsigned)o[3] << 16));
    }
}

// ---------------- conv(4) + bias + SiLU, vectorized (8 d per thread) ----------------
__global__ __launch_bounds__(256) void conv_silu(
    const ushort_t* __restrict__ xrb,   // BL x 4096 bf16 (xp = cols [0,2048))
    const float* __restrict__ convw,
    const float* __restrict__ convb,
    ushort_t* __restrict__ hb)          // BL x 2048 bf16
{
    const int bt = blockIdx.x;
    const int t  = bt & (SEQ - 1);
    const int d0 = threadIdx.x * 8;

    bf16x8 xv[DCONV];
    #pragma unroll
    for (int j = 0; j < DCONV; ++j) {
        int tt = t + j - (DCONV - 1);
        if (tt >= 0)
            xv[j] = *(const bf16x8*)(xrb + (size_t)(bt + j - (DCONV - 1)) * 4096 + d0);
        else
            xv[j] = (bf16x8){0,0,0,0,0,0,0,0};
    }

    ushort_t o[8];
    #pragma unroll
    for (int dd = 0; dd < 8; ++dd) {
        f32x4 w = *(const f32x4*)(convw + (size_t)(d0 + dd) * DCONV);
        float acc = convb[d0 + dd];
        #pragma unroll
        for (int j = 0; j < DCONV; ++j)
            acc = fmaf(w[j], bf2f((ushort_t)xv[j][dd]), acc);
        o[dd] = f2bf(acc * sigmoid_fast(acc));
    }
    uint4 pk;
    pk.x = (unsigned)o[0] | ((unsigned)o[1] << 16);
    pk.y = (unsigned)o[2] | ((unsigned)o[3] << 16);
    pk.z = (unsigned)o[4] | ((unsigned)o[5] << 16);
    pk.w = (unsigned)o[6] | ((unsigned)o[7] << 16);
    *(uint4*)(hb + (size_t)bt * DINNER + d0) = pk;
}

// ================= chunked parallel selective scan =================
__global__ __launch_bounds__(256) void scan_p1(
    const ushort_t* __restrict__ delta_bf,
    const ushort_t* __restrict__ hb,
    const float* __restrict__ xdbl,
    const float* __restrict__ Alog,
    float* __restrict__ Pbuf,
    float* __restrict__ Sbuf)
{
    const int d  = (blockIdx.x & 7) * 256 + threadIdx.x;
    const int bc = blockIdx.x >> 3;
    const int b  = bc >> 5;
    const int c  = bc & (NCHUNK - 1);
    const int t0 = c * TCHUNK;

    float A[NSTATE];
    #pragma unroll
    for (int q = 0; q < 4; ++q) {
        f32x4 al = *(const f32x4*)(Alog + (size_t)d * NSTATE + q * 4);
        #pragma unroll
        for (int j = 0; j < 4; ++j)
            A[q * 4 + j] = -hexp2(al[j] * LOG2E) * LOG2E;
    }

    float s[NSTATE], pp[NSTATE];
    #pragma unroll
    for (int n = 0; n < NSTATE; ++n) { s[n] = 0.f; pp[n] = 1.f; }

    for (int tt = 0; tt < TCHUNK; ++tt) {
        const size_t row = (size_t)(b * SEQ + t0 + tt);
        float dl = bf2f(delta_bf[row * DINNER + d]);
        float hv = bf2f(hb[row * DINNER + d]);
        float dlh = dl * hv;
        float Bv[NSTATE];
        #pragma unroll
        for (int q = 0; q < 4; ++q) {
            f32x4 bv = *(const f32x4*)(xdbl + row * XDBLW + DTRANK + q * 4);
            #pragma unroll
            for (int j = 0; j < 4; ++j) Bv[q * 4 + j] = bv[j];
        }
        #pragma unroll
        for (int n = 0; n < NSTATE; ++n) {
            float a = hexp2(dl * A[n]);
            s[n]  = fmaf(a, s[n], dlh * Bv[n]);
            pp[n] *= a;
        }
    }

    const size_t o = (((size_t)b * NCHUNK + c) * DINNER + d) * NSTATE;
    #pragma unroll
    for (int q = 0; q < 4; ++q) {
        *(f32x4*)(Sbuf + o + q * 4) = (f32x4){s[q*4+0], s[q*4+1], s[q*4+2], s[q*4+3]};
        *(f32x4*)(Pbuf + o + q * 4) = (f32x4){pp[q*4+0], pp[q*4+1], pp[q*4+2], pp[q*4+3]};
    }
}

// register-batched carry: load all chunk summaries (independent), chain in-reg, store
__global__ __launch_bounds__(256) void scan_p2(
    const float* __restrict__ Pbuf, float* __restrict__ Sbuf)
{
    const int tid = blockIdx.x * 256 + threadIdx.x;
    const int n = tid & 15;
    const int d = (tid >> 4) & (DINNER - 1);
    const int b = tid >> 15;
    const size_t stride = (size_t)DINNER * NSTATE;
    const size_t base = ((size_t)b * NCHUNK * DINNER + d) * NSTATE + n;

    float S[NCHUNK], P[NCHUNK];
    #pragma unroll
    for (int c = 0; c < NCHUNK; ++c) {
        S[c] = Sbuf[base + c * stride];
        P[c] = Pbuf[base + c * stride];
    }
    float cin = 0.f;
    float O[NCHUNK];
    #pragma unroll
    for (int c = 0; c < NCHUNK; ++c) {
        O[c] = cin;
        cin = fmaf(P[c], cin, S[c]);
    }
    #pragma unroll
    for (int c = 0; c < NCHUNK; ++c)
        Sbuf[base + c * stride] = O[c];
}

__global__ __launch_bounds__(256) void scan_p3(
    const ushort_t* __restrict__ delta_bf,
    const ushort_t* __restrict__ hb,
    const float* __restrict__ xdbl,
    const ushort_t* __restrict__ xrb,
    const float* __restrict__ Alog,
    const float* __restrict__ Dp,
    const float* __restrict__ Sbuf,
    ushort_t* __restrict__ yb)
{
    const int d  = (blockIdx.x & 7) * 256 + threadIdx.x;
    const int bc = blockIdx.x >> 3;
    const int b  = bc >> 5;
    const int c  = bc & (NCHUNK - 1);
    const int t0 = c * TCHUNK;

    float A[NSTATE];
    #pragma unroll
    for (int q = 0; q < 4; ++q) {
        f32x4 al = *(const f32x4*)(Alog + (size_t)d * NSTATE + q * 4);
        #pragma unroll
        for (int j = 0; j < 4; ++j)
            A[q * 4 + j] = -hexp2(al[j] * LOG2E) * LOG2E;
    }
    const float Dd = Dp[d];

    float s[NSTATE];
    const size_t o = (((size_t)b * NCHUNK + c) * DINNER + d) * NSTATE;
    #pragma unroll
    for (int q = 0; q < 4; ++q) {
        f32x4 sv = *(const f32x4*)(Sbuf + o + q * 4);
        #pragma unroll
        for (int j = 0; j < 4; ++j) s[q * 4 + j] = sv[j];
    }

    for (int tt = 0; tt < TCHUNK; ++tt) {
        const size_t row = (size_t)(b * SEQ + t0 + tt);
        float dl = bf2f(delta_bf[row * DINNER + d]);
        float hv = bf2f(hb[row * DINNER + d]);
        float rv = bf2f(xrb[row * 4096 + DINNER + d]);
        float dlh = dl * hv;
        float Bv[NSTATE], Cv[NSTATE];
        #pragma unroll
        for (int q = 0; q < 4; ++q) {
            f32x4 bv = *(const f32x4*)(xdbl + row * XDBLW + DTRANK + q * 4);
            f32x4 cv = *(const f32x4*)(xdbl + row * XDBLW + DTRANK + NSTATE + q * 4);
            #pragma unroll
            for (int j = 0; j < 4; ++j) { Bv[q*4+j] = bv[j]; Cv[q*4+j] = cv[j]; }
        }
        float y = 0.f;
        #pragma unroll
        for (int n = 0; n < NSTATE; ++n) {
            float a = hexp2(dl * A[n]);
            s[n] = fmaf(a, s[n], dlh * Bv[n]);
            y = fmaf(s[n], Cv[n], y);
        }
        y = fmaf(hv, Dd, y);
        y = y * rv * sigmoid_fast(rv);
        yb[row * DINNER + d] = f2bf(y);
    }
}

extern "C" void kernel_launch(void* const* d_in, const int* in_sizes, int n_in,
                              void* d_out, int out_size, void* d_ws, size_t ws_size,
                              hipStream_t stream)
{
    const float* x     = (const float*)d_in[0];
    const float* Win   = (const float*)d_in[1];
    const float* convw = (const float*)d_in[2];
    const float* convb = (const float*)d_in[3];
    const float* Wxp   = (const float*)d_in[4];
    const float* Wdt   = (const float*)d_in[5];
    const float* dtb   = (const float*)d_in[6];
    const float* Alog  = (const float*)d_in[7];
    const float* Dp    = (const float*)d_in[8];
    const float* Wout  = (const float*)d_in[9];
    float* out = (float*)d_out;

    char* base = (char*)d_ws; size_t off = 0;
    auto alloc = [&](size_t bytes) -> char* {
        char* q = base + off;
        off = (off + bytes + 255) & ~(size_t)255;
        return q;
    };
    ushort_t* WtIn   = (ushort_t*)alloc((size_t)4096 * 1024 * 2);
    ushort_t* WtOut  = (ushort_t*)alloc((size_t)1024 * 2048 * 2);
    ushort_t* WtXp   = (ushort_t*)alloc((size_t)96   * 2048 * 2);
    ushort_t* xb     = (ushort_t*)alloc((size_t)BL * DIM * 2);
    ushort_t* xrb    = (ushort_t*)alloc((size_t)BL * 4096 * 2);
    ushort_t* hb     = (ushort_t*)alloc((size_t)BL * DINNER * 2);
    float*    xdbl   = (float*)   alloc((size_t)BL * XDBLW * 4);
    ushort_t* dltbf  = (ushort_t*)alloc((size_t)BL * DINNER * 2);
    ushort_t* yb     = (ushort_t*)alloc((size_t)BL * DINNER * 2);
    float*    Pbuf   = (float*)   alloc((size_t)BATCH * NCHUNK * DINNER * NSTATE * 4);
    float*    Sbuf   = (float*)   alloc((size_t)BATCH * NCHUNK * DINNER * NSTATE * 4);
    float*    Ppart  = (float*)   alloc((size_t)KSLICE * BL * XDBLW * 4);
    float*    G4part = (float*)   alloc((size_t)G4SK * BL * DIM * 4);   // 32 MB
    (void)ws_size;

    prep_fused<<<dim3(8384), 256, 0, stream>>>(Win, WtIn, Wout, WtOut, Wxp, WtXp, x, xb);

    // G1: xr = x @ in_proj_w (2048 x 4096, K=1024) -> bf16; 128x128 tiles (proven best)
    gemm_lds<<<dim3(4096/128, BL/128), 256, 0, stream>>>(
        xb, DIM, WtIn, DIM, DIM, nullptr, xrb, 2*DINNER);

    conv_silu<<<dim3(BL), 256, 0, stream>>>(xrb, convw, convb, hb);

    gemm_n96_splitk<<<dim3(KSLICE, BL/128), 256, 0, stream>>>(hb, WtXp, Ppart);
    g2_reduce<<<dim3(BL * 24 / 256), 256, 0, stream>>>(Ppart, xdbl);

    delta_v6<<<dim3(8 * (BL / 32)), 256, 0, stream>>>(xdbl, Wdt, dtb, dltbf);

    scan_p1<<<dim3(8 * BATCH * NCHUNK), 256, 0, stream>>>(dltbf, hb, xdbl, Alog, Pbuf, Sbuf);
    scan_p2<<<dim3(BATCH * DINNER * NSTATE / 256), 256, 0, stream>>>(Pbuf, Sbuf);
    scan_p3<<<dim3(8 * BATCH * NCHUNK), 256, 0, stream>>>(dltbf, hb, xdbl, xrb, Alog, Dp, Sbuf, yb);

    // G4: out = y @ out_proj_w (2048 x 1024, K=2048) via split-K=4; 128x128 tiles
    gemm_lds_sk<<<dim3(DIM/128, BL/128, G4SK), 256, 0, stream>>>(
        yb, DINNER, WtOut, DINNER, DINNER/G4SK, G4part, DIM, BL*DIM);
    g4_reduce<<<dim3(BL*DIM/4/256), 256, 0, stream>>>(G4part, out);
}

// Round 22
// 139.703 us; speedup vs baseline: 1.0798x; 1.0046x over previous
//
#include <hip/hip_runtime.h>
#include <hip/hip_bf16.h>

// ---- problem dims (compile-time) ----
#define DIM     1024
#define DINNER  2048
#define NSTATE  16
#define DTRANK  64
#define DCONV   4
#define BATCH   2
#define SEQ     1024
#define BL      (BATCH*SEQ)     // 2048 rows
#define XDBLW   96              // DTRANK + 2*NSTATE
#define NCHUNK  32
#define TCHUNK  32              // SEQ / NCHUNK
#define KSLICE  16              // split-K factor for G2
#define G4SK    4               // split-K factor for G4
#define LOG2E   1.44269504088896f
#define LN2     0.69314718055995f

typedef __attribute__((ext_vector_type(4))) float  f32x4;
typedef __attribute__((ext_vector_type(8))) short  bf16x8;
typedef unsigned short ushort_t;

__device__ __forceinline__ ushort_t f2bf(float f) {
    union { float f; unsigned int u; } v; v.f = f;
    unsigned int lsb = (v.u >> 16) & 1u;
    v.u += 0x7fffu + lsb;
    return (ushort_t)(v.u >> 16);
}
__device__ __forceinline__ float bf2f(ushort_t h) {
    union { unsigned u; float f; } v; v.u = ((unsigned)h) << 16; return v.f;
}
// HW-instruction transcendentals (v_exp_f32 = 2^x, v_log_f32 = log2, v_rcp_f32)
__device__ __forceinline__ float hexp2(float x) { return __builtin_amdgcn_exp2f(x); }
__device__ __forceinline__ float hlog2(float x) { return __builtin_amdgcn_logf(x); }
__device__ __forceinline__ float hrcp(float x)  { return __builtin_amdgcn_rcpf(x); }
__device__ __forceinline__ float softplus_fast(float x) {
    float e = hexp2(-fabsf(x) * LOG2E);
    return fmaxf(x, 0.f) + LN2 * hlog2(1.f + e);
}
__device__ __forceinline__ float sigmoid_fast(float x) {
    return hrcp(1.f + hexp2(-x * LOG2E));
}

typedef __attribute__((address_space(1))) unsigned int gu32_t;
typedef __attribute__((address_space(3))) unsigned int lu32_t;
__device__ __forceinline__ void gload_lds16(const ushort_t* g, ushort_t* l) {
    __builtin_amdgcn_global_load_lds((const gu32_t*)(const void*)g,
                                     (lu32_t*)(void*)l, 16, 0, 0);
}

// ================= fused prep: 3 weight transposes + x convert =================
__global__ __launch_bounds__(256) void prep_fused(
    const float* __restrict__ Win,  ushort_t* __restrict__ WtIn,
    const float* __restrict__ Wout, ushort_t* __restrict__ WtOut,
    const float* __restrict__ Wxp,  ushort_t* __restrict__ WtXp,
    const float* __restrict__ x,    ushort_t* __restrict__ xb)
{
    __shared__ float tile[32][33];
    const int tid = threadIdx.x;
    const int tx = tid & 31, ty = tid >> 5;
    const int bid = blockIdx.x;

    const float* src; ushort_t* dst; int R, C, bx, by;
    if (bid < 4096)      { src = Win;  dst = WtIn;  R = 1024; C = 4096; int j = bid;        bx = j % 128; by = j / 128; }
    else if (bid < 6144) { src = Wout; dst = WtOut; R = 2048; C = 1024; int j = bid - 4096; bx = j % 32;  by = j / 32; }
    else if (bid < 6336) { src = Wxp;  dst = WtXp;  R = 2048; C = 96;   int j = bid - 6144; bx = j % 3;   by = j / 3; }
    else {
        int i = ((bid - 6336) * 256 + tid) * 4;
        f32x4 v = *(const f32x4*)(x + i);
        ushort_t r0 = f2bf(v[0]), r1 = f2bf(v[1]), r2 = f2bf(v[2]), r3 = f2bf(v[3]);
        *(uint2*)(xb + i) = make_uint2((unsigned)r0 | ((unsigned)r1 << 16),
                                       (unsigned)r2 | ((unsigned)r3 << 16));
        return;
    }

    const int r0 = by * 32, c0 = bx * 32;
    #pragma unroll
    for (int i = 0; i < 4; ++i)
        tile[ty + i * 8][tx] = src[(size_t)(r0 + ty + i * 8) * C + c0 + tx];
    __syncthreads();
    #pragma unroll
    for (int i = 0; i < 4; ++i)
        dst[(size_t)(c0 + ty + i * 8) * R + r0 + tx] = f2bf(tile[tx][ty + i * 8]);
}

// ======== MFMA GEMM: 128x128 tile, BK=64, dbuf, XOR-swizzle, 8 WAVES/BLOCK ========
// 512 threads: same grid & LDS (2 blocks/CU) but 16 waves/CU = 4/SIMD for latency
// hiding. Wave = 64x32 output (acc[4][2]). Staging 2 chunks/matrix/thread, vmcnt(4).
__global__ __launch_bounds__(512) void gemm_lds(
    const ushort_t* __restrict__ A,  int lda,
    const ushort_t* __restrict__ Bt, int ldb,
    int K,
    float* __restrict__ Cf, ushort_t* __restrict__ Cb, int ldc)
{
    __shared__ ushort_t As[2][128 * 64];
    __shared__ ushort_t Bs[2][128 * 64];

    const int tid  = threadIdx.x;
    const int m0   = blockIdx.y * 128;
    const int n0   = blockIdx.x * 128;
    const int wid  = tid >> 6;          // 0..7
    const int lane = tid & 63;
    const int wm   = (wid >> 2) * 64;   // 2 m-groups
    const int wn   = (wid & 3) * 32;    // 4 n-groups
    const int lr   = lane & 15;

    int rq[2], gq[2], lo[2];
    #pragma unroll
    for (int q = 0; q < 2; ++q) {
        int c = q * 512 + tid;              // chunk 0..1023
        rq[q] = c >> 3;
        gq[q] = ((c & 7) ^ (rq[q] & 7)) * 8;
        lo[q] = (q * 512 + wid * 64) * 8;   // wave-uniform base, lane-contig
    }

    f32x4 acc[4][2];
    #pragma unroll
    for (int m = 0; m < 4; ++m)
        #pragma unroll
        for (int n = 0; n < 2; ++n)
            acc[m][n] = (f32x4){0.f, 0.f, 0.f, 0.f};

    const int nk = K >> 6;

    #pragma unroll
    for (int q = 0; q < 2; ++q) {
        gload_lds16(A  + (size_t)(m0 + rq[q]) * lda + gq[q], &As[0][lo[q]]);
        gload_lds16(Bt + (size_t)(n0 + rq[q]) * ldb + gq[q], &Bs[0][lo[q]]);
    }

    for (int k = 0; k < nk; ++k) {
        const int cur = k & 1;
        if (k + 1 < nk) {
            const int k0 = (k + 1) << 6;
            #pragma unroll
            for (int q = 0; q < 2; ++q) {
                gload_lds16(A  + (size_t)(m0 + rq[q]) * lda + k0 + gq[q], &As[cur ^ 1][lo[q]]);
                gload_lds16(Bt + (size_t)(n0 + rq[q]) * ldb + k0 + gq[q], &Bs[cur ^ 1][lo[q]]);
            }
            asm volatile("s_waitcnt vmcnt(4)" ::: "memory");   // tile k landed; k+1 in flight
        } else {
            asm volatile("s_waitcnt vmcnt(0)" ::: "memory");
        }
        __builtin_amdgcn_sched_barrier(0);
        __builtin_amdgcn_s_barrier();

        #pragma unroll
        for (int kk = 0; kk < 2; ++kk) {
            const int lg = (lane >> 4) + kk * 4;
            const int pc = (lg ^ (lr & 7)) * 8;
            bf16x8 af[4], bfr[2];
            #pragma unroll
            for (int m = 0; m < 4; ++m)
                af[m] = *(const bf16x8*)(&As[cur][(wm + m * 16 + lr) * 64 + pc]);
            #pragma unroll
            for (int n = 0; n < 2; ++n)
                bfr[n] = *(const bf16x8*)(&Bs[cur][(wn + n * 16 + lr) * 64 + pc]);
            #pragma unroll
            for (int m = 0; m < 4; ++m)
                #pragma unroll
                for (int n = 0; n < 2; ++n)
                    acc[m][n] = __builtin_amdgcn_mfma_f32_16x16x32_bf16(af[m], bfr[n], acc[m][n], 0, 0, 0);
        }
        __builtin_amdgcn_s_barrier();
    }

    const int rbase = (lane >> 4) * 4;
    #pragma unroll
    for (int m = 0; m < 4; ++m) {
        #pragma unroll
        for (int n = 0; n < 2; ++n) {
            int col = n0 + wn + n * 16 + lr;
            #pragma unroll
            for (int r = 0; r < 4; ++r) {
                int row = m0 + wm + m * 16 + rbase + r;
                float v = acc[m][n][r];
                if (Cf) Cf[(size_t)row * ldc + col] = v;
                if (Cb) Cb[(size_t)row * ldc + col] = f2bf(v);
            }
        }
    }
}

// ======== G4 split-K variant, same 8-wave 128x128 pipeline ========
__global__ __launch_bounds__(512) void gemm_lds_sk(
    const ushort_t* __restrict__ A,  int lda,
    const ushort_t* __restrict__ Bt, int ldb,
    int klen,
    float* __restrict__ Part, int ldc, int mn)   // Part[z][M][ldc]
{
    __shared__ ushort_t As[2][128 * 64];
    __shared__ ushort_t Bs[2][128 * 64];

    const int tid  = threadIdx.x;
    const int m0   = blockIdx.y * 128;
    const int n0   = blockIdx.x * 128;
    const int kb   = blockIdx.z * klen;
    float* Cf = Part + (size_t)blockIdx.z * mn;

    const int wid  = tid >> 6;
    const int lane = tid & 63;
    const int wm   = (wid >> 2) * 64;
    const int wn   = (wid & 3) * 32;
    const int lr   = lane & 15;

    int rq[2], gq[2], lo[2];
    #pragma unroll
    for (int q = 0; q < 2; ++q) {
        int c = q * 512 + tid;
        rq[q] = c >> 3;
        gq[q] = ((c & 7) ^ (rq[q] & 7)) * 8;
        lo[q] = (q * 512 + wid * 64) * 8;
    }

    f32x4 acc[4][2];
    #pragma unroll
    for (int m = 0; m < 4; ++m)
        #pragma unroll
        for (int n = 0; n < 2; ++n)
            acc[m][n] = (f32x4){0.f, 0.f, 0.f, 0.f};

    const int nk = klen >> 6;

    #pragma unroll
    for (int q = 0; q < 2; ++q) {
        gload_lds16(A  + (size_t)(m0 + rq[q]) * lda + kb + gq[q], &As[0][lo[q]]);
        gload_lds16(Bt + (size_t)(n0 + rq[q]) * ldb + kb + gq[q], &Bs[0][lo[q]]);
    }

    for (int k = 0; k < nk; ++k) {
        const int cur = k & 1;
        if (k + 1 < nk) {
            const int k0 = kb + ((k + 1) << 6);
            #pragma unroll
            for (int q = 0; q < 2; ++q) {
                gload_lds16(A  + (size_t)(m0 + rq[q]) * lda + k0 + gq[q], &As[cur ^ 1][lo[q]]);
                gload_lds16(Bt + (size_t)(n0 + rq[q]) * ldb + k0 + gq[q], &Bs[cur ^ 1][lo[q]]);
            }
            asm volatile("s_waitcnt vmcnt(4)" ::: "memory");
        } else {
            asm volatile("s_waitcnt vmcnt(0)" ::: "memory");
        }
        __builtin_amdgcn_sched_barrier(0);
        __builtin_amdgcn_s_barrier();

        #pragma unroll
        for (int kk = 0; kk < 2; ++kk) {
            const int lg = (lane >> 4) + kk * 4;
            const int pc = (lg ^ (lr & 7)) * 8;
            bf16x8 af[4], bfr[2];
            #pragma unroll
            for (int m = 0; m < 4; ++m)
                af[m] = *(const bf16x8*)(&As[cur][(wm + m * 16 + lr) * 64 + pc]);
            #pragma unroll
            for (int n = 0; n < 2; ++n)
                bfr[n] = *(const bf16x8*)(&Bs[cur][(wn + n * 16 + lr) * 64 + pc]);
            #pragma unroll
            for (int m = 0; m < 4; ++m)
                #pragma unroll
                for (int n = 0; n < 2; ++n)
                    acc[m][n] = __builtin_amdgcn_mfma_f32_16x16x32_bf16(af[m], bfr[n], acc[m][n], 0, 0, 0);
        }
        __builtin_amdgcn_s_barrier();
    }

    const int rbase = (lane >> 4) * 4;
    #pragma unroll
    for (int m = 0; m < 4; ++m) {
        #pragma unroll
        for (int n = 0; n < 2; ++n) {
            int col = n0 + wn + n * 16 + lr;
            #pragma unroll
            for (int r = 0; r < 4; ++r) {
                int row = m0 + wm + m * 16 + rbase + r;
                Cf[(size_t)row * ldc + col] = acc[m][n][r];
            }
        }
    }
}

// sum G4SK partials -> f32 out
__global__ __launch_bounds__(256) void g4_reduce(
    const float* __restrict__ Part, float* __restrict__ out)
{
    int i = (blockIdx.x * 256 + threadIdx.x) * 4;
    const size_t mn = (size_t)BL * DIM;
    f32x4 s = *(const f32x4*)(Part + i);
    #pragma unroll
    for (int z = 1; z < G4SK; ++z)
        s += *(const f32x4*)(Part + z * mn + i);
    *(f32x4*)(out + i) = s;
}

// ======== G2 split-K ========
__global__ __launch_bounds__(256) void gemm_n96_splitk(
    const ushort_t* __restrict__ A,
    const ushort_t* __restrict__ Bt,
    float* __restrict__ Ppart)
{
    __shared__ ushort_t As[128 * 40];
    __shared__ ushort_t Bs[96 * 40];

    const int tid   = threadIdx.x;
    const int ks    = blockIdx.x;
    const int m0    = blockIdx.y * 128;
    const int kbase = ks * (DINNER / KSLICE);
    const int wid   = tid >> 6;
    const int lane  = tid & 63;
    const int wm    = wid * 32;
    const int lr    = lane & 15;
    const int lk    = (lane >> 4) * 8;

    f32x4 acc[2][6];
    #pragma unroll
    for (int m = 0; m < 2; ++m)
        #pragma unroll
        for (int n = 0; n < 6; ++n)
            acc[m][n] = (f32x4){0.f, 0.f, 0.f, 0.f};

    for (int k0 = kbase; k0 < kbase + DINNER / KSLICE; k0 += 32) {
        #pragma unroll
        for (int c = 0; c < 2; ++c) {
            int cid = tid + c * 256;
            int row = cid >> 2, ck = (cid & 3) * 8;
            *(uint4*)(&As[row * 40 + ck]) =
                *(const uint4*)(A + (size_t)(m0 + row) * DINNER + k0 + ck);
        }
        {
            int row = tid >> 2, ck = (tid & 3) * 8;
            *(uint4*)(&Bs[row * 40 + ck]) =
                *(const uint4*)(Bt + (size_t)row * DINNER + k0 + ck);
            if (tid < 128) {
                int cid = 256 + tid;
                int row2 = cid >> 2, ck2 = (cid & 3) * 8;
                *(uint4*)(&Bs[row2 * 40 + ck2]) =
                    *(const uint4*)(Bt + (size_t)row2 * DINNER + k0 + ck2);
            }
        }
        __syncthreads();

        bf16x8 af[2], bfr[6];
        #pragma unroll
        for (int m = 0; m < 2; ++m)
            af[m] = *(const bf16x8*)(&As[(wm + m * 16 + lr) * 40 + lk]);
        #pragma unroll
        for (int n = 0; n < 6; ++n)
            bfr[n] = *(const bf16x8*)(&Bs[(n * 16 + lr) * 40 + lk]);

        #pragma unroll
        for (int m = 0; m < 2; ++m)
            #pragma unroll
            for (int n = 0; n < 6; ++n)
                acc[m][n] = __builtin_amdgcn_mfma_f32_16x16x32_bf16(af[m], bfr[n], acc[m][n], 0, 0, 0);
        __syncthreads();
    }

    const int rbase = (lane >> 4) * 4;
    #pragma unroll
    for (int m = 0; m < 2; ++m) {
        #pragma unroll
        for (int n = 0; n < 6; ++n) {
            int col = n * 16 + lr;
            #pragma unroll
            for (int r = 0; r < 4; ++r) {
                int row = m0 + wm + m * 16 + rbase + r;
                Ppart[((size_t)ks * BL + row) * XDBLW + col] = acc[m][n][r];
            }
        }
    }
}

// reduce split-K partials -> xdbl
__global__ __launch_bounds__(256) void g2_reduce(
    const float* __restrict__ Ppart, float* __restrict__ xdbl)
{
    int idx = blockIdx.x * 256 + threadIdx.x;
    int row = idx / 24, cg = (idx % 24) * 4;
    f32x4 s = (f32x4){0.f, 0.f, 0.f, 0.f};
    #pragma unroll
    for (int ks = 0; ks < KSLICE; ++ks)
        s += *(const f32x4*)(Ppart + ((size_t)ks * BL + row) * XDBLW + cg);
    *(f32x4*)(xdbl + (size_t)row * XDBLW + cg) = s;
}

// ======== delta_v6: packed layout + fast softplus ========
__global__ __launch_bounds__(256, 4) void delta_v6(
    const float* __restrict__ xdbl,
    const float* __restrict__ Wdt,
    const float* __restrict__ dtb,
    ushort_t* __restrict__ delta_bf)
{
    __shared__ float WS[64][256];
    __shared__ float dS[32][64];
    const int tid  = threadIdx.x;
    const int d0   = (blockIdx.x & 7) * 256;
    const int row0 = (blockIdx.x >> 3) * 32;

    #pragma unroll
    for (int i = 0; i < 16; ++i) {
        int c = i * 256 + tid;
        int k = c >> 6, co = (c & 63) * 4;
        *(f32x4*)&WS[k][co] = *(const f32x4*)(Wdt + (size_t)k * DINNER + d0 + co);
    }
    #pragma unroll
    for (int i = 0; i < 2; ++i) {
        int c = i * 256 + tid;
        int r = c >> 4, co = (c & 15) * 4;
        *(f32x4*)&dS[r][co] = *(const f32x4*)(xdbl + (size_t)(row0 + r) * XDBLW + co);
    }
    __syncthreads();

    const int w    = tid >> 6;
    const int lane = tid & 63;
    const int dd   = lane * 4;

    f32x4 acc[8];
    {
        f32x4 bb = *(const f32x4*)(dtb + d0 + dd);
        #pragma unroll
        for (int r = 0; r < 8; ++r) acc[r] = bb;
    }

    for (int kq = 0; kq < 16; ++kq) {
        f32x4 dv[8];
        #pragma unroll
        for (int r = 0; r < 8; ++r)
            dv[r] = *(const f32x4*)&dS[w * 8 + r][kq * 4];
        #pragma unroll
        for (int kk = 0; kk < 4; ++kk) {
            f32x4 wv = *(const f32x4*)&WS[kq * 4 + kk][dd];
            #pragma unroll
            for (int r = 0; r < 8; ++r) {
                float dk = dv[r][kk];
                acc[r][0] = fmaf(dk, wv[0], acc[r][0]);
                acc[r][1] = fmaf(dk, wv[1], acc[r][1]);
                acc[r][2] = fmaf(dk, wv[2], acc[r][2]);
                acc[r][3] = fmaf(dk, wv[3], acc[r][3]);
            }
        }
    }

    #pragma unroll
    for (int r = 0; r < 8; ++r) {
        const size_t rowb = (size_t)(row0 + w * 8 + r) * DINNER + d0;
        f32x4 v = acc[r];
        ushort_t o[4];
        #pragma unroll
        for (int j = 0; j < 4; ++j)
            o[j] = f2bf(softplus_fast(v[j]));
        *(uint2*)(delta_bf + rowb + dd) = make_uint2(
            (unsigned)o[0] | ((unsigned)o[1] << 16), (unsigned)o[2] | ((unsigned)o[3] << 16));
    }
}

// ---------------- conv(4) + bias + SiLU, vectorized (8 d per thread) ----------------
__global__ __launch_bounds__(256) void conv_silu(
    const ushort_t* __restrict__ xrb,   // BL x 4096 bf16 (xp = cols [0,2048))
    const float* __restrict__ convw,
    const float* __restrict__ convb,
    ushort_t* __restrict__ hb)          // BL x 2048 bf16
{
    const int bt = blockIdx.x;
    const int t  = bt & (SEQ - 1);
    const int d0 = threadIdx.x * 8;

    bf16x8 xv[DCONV];
    #pragma unroll
    for (int j = 0; j < DCONV; ++j) {
        int tt = t + j - (DCONV - 1);
        if (tt >= 0)
            xv[j] = *(const bf16x8*)(xrb + (size_t)(bt + j - (DCONV - 1)) * 4096 + d0);
        else
            xv[j] = (bf16x8){0,0,0,0,0,0,0,0};
    }

    ushort_t o[8];
    #pragma unroll
    for (int dd = 0; dd < 8; ++dd) {
        f32x4 w = *(const f32x4*)(convw + (size_t)(d0 + dd) * DCONV);
        float acc = convb[d0 + dd];
        #pragma unroll
        for (int j = 0; j < DCONV; ++j)
            acc = fmaf(w[j], bf2f((ushort_t)xv[j][dd]), acc);
        o[dd] = f2bf(acc * sigmoid_fast(acc));
    }
    uint4 pk;
    pk.x = (unsigned)o[0] | ((unsigned)o[1] << 16);
    pk.y = (unsigned)o[2] | ((unsigned)o[3] << 16);
    pk.z = (unsigned)o[4] | ((unsigned)o[5] << 16);
    pk.w = (unsigned)o[6] | ((unsigned)o[7] << 16);
    *(uint4*)(hb + (size_t)bt * DINNER + d0) = pk;
}

// ================= chunked parallel selective scan =================
__global__ __launch_bounds__(256) void scan_p1(
    const ushort_t* __restrict__ delta_bf,
    const ushort_t* __restrict__ hb,
    const float* __restrict__ xdbl,
    const float* __restrict__ Alog,
    float* __restrict__ Pbuf,
    float* __restrict__ Sbuf)
{
    const int d  = (blockIdx.x & 7) * 256 + threadIdx.x;
    const int bc = blockIdx.x >> 3;
    const int b  = bc >> 5;
    const int c  = bc & (NCHUNK - 1);
    const int t0 = c * TCHUNK;

    float A[NSTATE];
    #pragma unroll
    for (int q = 0; q < 4; ++q) {
        f32x4 al = *(const f32x4*)(Alog + (size_t)d * NSTATE + q * 4);
        #pragma unroll
        for (int j = 0; j < 4; ++j)
            A[q * 4 + j] = -hexp2(al[j] * LOG2E) * LOG2E;
    }

    float s[NSTATE], pp[NSTATE];
    #pragma unroll
    for (int n = 0; n < NSTATE; ++n) { s[n] = 0.f; pp[n] = 1.f; }

    for (int tt = 0; tt < TCHUNK; ++tt) {
        const size_t row = (size_t)(b * SEQ + t0 + tt);
        float dl = bf2f(delta_bf[row * DINNER + d]);
        float hv = bf2f(hb[row * DINNER + d]);
        float dlh = dl * hv;
        float Bv[NSTATE];
        #pragma unroll
        for (int q = 0; q < 4; ++q) {
            f32x4 bv = *(const f32x4*)(xdbl + row * XDBLW + DTRANK + q * 4);
            #pragma unroll
            for (int j = 0; j < 4; ++j) Bv[q * 4 + j] = bv[j];
        }
        #pragma unroll
        for (int n = 0; n < NSTATE; ++n) {
            float a = hexp2(dl * A[n]);
            s[n]  = fmaf(a, s[n], dlh * Bv[n]);
            pp[n] *= a;
        }
    }

    const size_t o = (((size_t)b * NCHUNK + c) * DINNER + d) * NSTATE;
    #pragma unroll
    for (int q = 0; q < 4; ++q) {
        *(f32x4*)(Sbuf + o + q * 4) = (f32x4){s[q*4+0], s[q*4+1], s[q*4+2], s[q*4+3]};
        *(f32x4*)(Pbuf + o + q * 4) = (f32x4){pp[q*4+0], pp[q*4+1], pp[q*4+2], pp[q*4+3]};
    }
}

// register-batched carry: load all chunk summaries (independent), chain in-reg, store
__global__ __launch_bounds__(256) void scan_p2(
    const float* __restrict__ Pbuf, float* __restrict__ Sbuf)
{
    const int tid = blockIdx.x * 256 + threadIdx.x;
    const int n = tid & 15;
    const int d = (tid >> 4) & (DINNER - 1);
    const int b = tid >> 15;
    const size_t stride = (size_t)DINNER * NSTATE;
    const size_t base = ((size_t)b * NCHUNK * DINNER + d) * NSTATE + n;

    float S[NCHUNK], P[NCHUNK];
    #pragma unroll
    for (int c = 0; c < NCHUNK; ++c) {
        S[c] = Sbuf[base + c * stride];
        P[c] = Pbuf[base + c * stride];
    }
    float cin = 0.f;
    float O[NCHUNK];
    #pragma unroll
    for (int c = 0; c < NCHUNK; ++c) {
        O[c] = cin;
        cin = fmaf(P[c], cin, S[c]);
    }
    #pragma unroll
    for (int c = 0; c < NCHUNK; ++c)
        Sbuf[base + c * stride] = O[c];
}

__global__ __launch_bounds__(256) void scan_p3(
    const ushort_t* __restrict__ delta_bf,
    const ushort_t* __restrict__ hb,
    const float* __restrict__ xdbl,
    const ushort_t* __restrict__ xrb,
    const float* __restrict__ Alog,
    const float* __restrict__ Dp,
    const float* __restrict__ Sbuf,
    ushort_t* __restrict__ yb)
{
    const int d  = (blockIdx.x & 7) * 256 + threadIdx.x;
    const int bc = blockIdx.x >> 3;
    const int b  = bc >> 5;
    const int c  = bc & (NCHUNK - 1);
    const int t0 = c * TCHUNK;

    float A[NSTATE];
    #pragma unroll
    for (int q = 0; q < 4; ++q) {
        f32x4 al = *(const f32x4*)(Alog + (size_t)d * NSTATE + q * 4);
        #pragma unroll
        for (int j = 0; j < 4; ++j)
            A[q * 4 + j] = -hexp2(al[j] * LOG2E) * LOG2E;
    }
    const float Dd = Dp[d];

    float s[NSTATE];
    const size_t o = (((size_t)b * NCHUNK + c) * DINNER + d) * NSTATE;
    #pragma unroll
    for (int q = 0; q < 4; ++q) {
        f32x4 sv = *(const f32x4*)(Sbuf + o + q * 4);
        #pragma unroll
        for (int j = 0; j < 4; ++j) s[q * 4 + j] = sv[j];
    }

    for (int tt = 0; tt < TCHUNK; ++tt) {
        const size_t row = (size_t)(b * SEQ + t0 + tt);
        float dl = bf2f(delta_bf[row * DINNER + d]);
        float hv = bf2f(hb[row * DINNER + d]);
        float rv = bf2f(xrb[row * 4096 + DINNER + d]);
        float dlh = dl * hv;
        float Bv[NSTATE], Cv[NSTATE];
        #pragma unroll
        for (int q = 0; q < 4; ++q) {
            f32x4 bv = *(const f32x4*)(xdbl + row * XDBLW + DTRANK + q * 4);
            f32x4 cv = *(const f32x4*)(xdbl + row * XDBLW + DTRANK + NSTATE + q * 4);
            #pragma unroll
            for (int j = 0; j < 4; ++j) { Bv[q*4+j] = bv[j]; Cv[q*4+j] = cv[j]; }
        }
        float y = 0.f;
        #pragma unroll
        for (int n = 0; n < NSTATE; ++n) {
            float a = hexp2(dl * A[n]);
            s[n] = fmaf(a, s[n], dlh * Bv[n]);
            y = fmaf(s[n], Cv[n], y);
        }
        y = fmaf(hv, Dd, y);
        y = y * rv * sigmoid_fast(rv);
        yb[row * DINNER + d] = f2bf(y);
    }
}

extern "C" void kernel_launch(void* const* d_in, const int* in_sizes, int n_in,
                              void* d_out, int out_size, void* d_ws, size_t ws_size,
                              hipStream_t stream)
{
    const float* x     = (const float*)d_in[0];
    const float* Win   = (const float*)d_in[1];
    const float* convw = (const float*)d_in[2];
    const float* convb = (const float*)d_in[3];
    const float* Wxp   = (const float*)d_in[4];
    const float* Wdt   = (const float*)d_in[5];
    const float* dtb   = (const float*)d_in[6];
    const float* Alog  = (const float*)d_in[7];
    const float* Dp    = (const float*)d_in[8];
    const float* Wout  = (const float*)d_in[9];
    float* out = (float*)d_out;

    char* base = (char*)d_ws; size_t off = 0;
    auto alloc = [&](size_t bytes) -> char* {
        char* q = base + off;
        off = (off + bytes + 255) & ~(size_t)255;
        return q;
    };
    ushort_t* WtIn   = (ushort_t*)alloc((size_t)4096 * 1024 * 2);
    ushort_t* WtOut  = (ushort_t*)alloc((size_t)1024 * 2048 * 2);
    ushort_t* WtXp   = (ushort_t*)alloc((size_t)96   * 2048 * 2);
    ushort_t* xb     = (ushort_t*)alloc((size_t)BL * DIM * 2);
    ushort_t* xrb    = (ushort_t*)alloc((size_t)BL * 4096 * 2);
    ushort_t* hb     = (ushort_t*)alloc((size_t)BL * DINNER * 2);
    float*    xdbl   = (float*)   alloc((size_t)BL * XDBLW * 4);
    ushort_t* dltbf  = (ushort_t*)alloc((size_t)BL * DINNER * 2);
    ushort_t* yb     = (ushort_t*)alloc((size_t)BL * DINNER * 2);
    float*    Pbuf   = (float*)   alloc((size_t)BATCH * NCHUNK * DINNER * NSTATE * 4);
    float*    Sbuf   = (float*)   alloc((size_t)BATCH * NCHUNK * DINNER * NSTATE * 4);
    float*    Ppart  = (float*)   alloc((size_t)KSLICE * BL * XDBLW * 4);
    float*    G4part = (float*)   alloc((size_t)G4SK * BL * DIM * 4);   // 32 MB
    (void)ws_size;

    prep_fused<<<dim3(8384), 256, 0, stream>>>(Win, WtIn, Wout, WtOut, Wxp, WtXp, x, xb);

    // G1: xr = x @ in_proj_w (2048 x 4096, K=1024) -> bf16; 128x128, 8 waves/block
    gemm_lds<<<dim3(4096/128, BL/128), 512, 0, stream>>>(
        xb, DIM, WtIn, DIM, DIM, nullptr, xrb, 2*DINNER);

    conv_silu<<<dim3(BL), 256, 0, stream>>>(xrb, convw, convb, hb);

    gemm_n96_splitk<<<dim3(KSLICE, BL/128), 256, 0, stream>>>(hb, WtXp, Ppart);
    g2_reduce<<<dim3(BL * 24 / 256), 256, 0, stream>>>(Ppart, xdbl);

    delta_v6<<<dim3(8 * (BL / 32)), 256, 0, stream>>>(xdbl, Wdt, dtb, dltbf);

    scan_p1<<<dim3(8 * BATCH * NCHUNK), 256, 0, stream>>>(dltbf, hb, xdbl, Alog, Pbuf, Sbuf);
    scan_p2<<<dim3(BATCH * DINNER * NSTATE / 256), 256, 0, stream>>>(Pbuf, Sbuf);
    scan_p3<<<dim3(8 * BATCH * NCHUNK), 256, 0, stream>>>(dltbf, hb, xdbl, xrb, Alog, Dp, Sbuf, yb);

    // G4: out = y @ out_proj_w (2048 x 1024, K=2048) via split-K=4; 8 waves/block
    gemm_lds_sk<<<dim3(DIM/128, BL/128, G4SK), 512, 0, stream>>>(
        yb, DINNER, WtOut, DINNER, DINNER/G4SK, G4part, DIM, BL*DIM);
    g4_reduce<<<dim3(BL*DIM/4/256), 256, 0, stream>>>(G4part, out);
}

// Round 23
// 138.792 us; speedup vs baseline: 1.0869x; 1.0066x over previous
//
#include <hip/hip_runtime.h>
#include <hip/hip_bf16.h>

// ---- problem dims (compile-time) ----
#define DIM     1024
#define DINNER  2048
#define NSTATE  16
#define DTRANK  64
#define DCONV   4
#define BATCH   2
#define SEQ     1024
#define BL      (BATCH*SEQ)     // 2048 rows
#define XDBLW   96              // DTRANK + 2*NSTATE
#define NCHUNK  32
#define TCHUNK  32              // SEQ / NCHUNK
#define KSLICE  16              // split-K factor for G2
#define G4SK    4               // split-K factor for G4
#define LOG2E   1.44269504088896f
#define LN2     0.69314718055995f

typedef __attribute__((ext_vector_type(4))) float  f32x4;
typedef __attribute__((ext_vector_type(8))) short  bf16x8;
typedef unsigned short ushort_t;

__device__ __forceinline__ ushort_t f2bf(float f) {
    union { float f; unsigned int u; } v; v.f = f;
    unsigned int lsb = (v.u >> 16) & 1u;
    v.u += 0x7fffu + lsb;
    return (ushort_t)(v.u >> 16);
}
__device__ __forceinline__ float bf2f(ushort_t h) {
    union { unsigned u; float f; } v; v.u = ((unsigned)h) << 16; return v.f;
}
__device__ __forceinline__ void unpack_bf2(unsigned u, float& lo, float& hi) {
    union { unsigned x; float f; } a, b;
    a.x = u << 16; b.x = u & 0xffff0000u;
    lo = a.f; hi = b.f;
}
// HW-instruction transcendentals (v_exp_f32 = 2^x, v_log_f32 = log2, v_rcp_f32)
__device__ __forceinline__ float hexp2(float x) { return __builtin_amdgcn_exp2f(x); }
__device__ __forceinline__ float hlog2(float x) { return __builtin_amdgcn_logf(x); }
__device__ __forceinline__ float hrcp(float x)  { return __builtin_amdgcn_rcpf(x); }
__device__ __forceinline__ float softplus_fast(float x) {
    float e = hexp2(-fabsf(x) * LOG2E);
    return fmaxf(x, 0.f) + LN2 * hlog2(1.f + e);
}
__device__ __forceinline__ float sigmoid_fast(float x) {
    return hrcp(1.f + hexp2(-x * LOG2E));
}

typedef __attribute__((address_space(1))) unsigned int gu32_t;
typedef __attribute__((address_space(3))) unsigned int lu32_t;
__device__ __forceinline__ void gload_lds16(const ushort_t* g, ushort_t* l) {
    __builtin_amdgcn_global_load_lds((const gu32_t*)(const void*)g,
                                     (lu32_t*)(void*)l, 16, 0, 0);
}

// ================= fused prep: 3 weight transposes + x convert =================
__global__ __launch_bounds__(256) void prep_fused(
    const float* __restrict__ Win,  ushort_t* __restrict__ WtIn,
    const float* __restrict__ Wout, ushort_t* __restrict__ WtOut,
    const float* __restrict__ Wxp,  ushort_t* __restrict__ WtXp,
    const float* __restrict__ x,    ushort_t* __restrict__ xb)
{
    __shared__ float tile[32][33];
    const int tid = threadIdx.x;
    const int tx = tid & 31, ty = tid >> 5;
    const int bid = blockIdx.x;

    const float* src; ushort_t* dst; int R, C, bx, by;
    if (bid < 4096)      { src = Win;  dst = WtIn;  R = 1024; C = 4096; int j = bid;        bx = j % 128; by = j / 128; }
    else if (bid < 6144) { src = Wout; dst = WtOut; R = 2048; C = 1024; int j = bid - 4096; bx = j % 32;  by = j / 32; }
    else if (bid < 6336) { src = Wxp;  dst = WtXp;  R = 2048; C = 96;   int j = bid - 6144; bx = j % 3;   by = j / 3; }
    else {
        int i = ((bid - 6336) * 256 + tid) * 4;
        f32x4 v = *(const f32x4*)(x + i);
        ushort_t r0 = f2bf(v[0]), r1 = f2bf(v[1]), r2 = f2bf(v[2]), r3 = f2bf(v[3]);
        *(uint2*)(xb + i) = make_uint2((unsigned)r0 | ((unsigned)r1 << 16),
                                       (unsigned)r2 | ((unsigned)r3 << 16));
        return;
    }

    const int r0 = by * 32, c0 = bx * 32;
    #pragma unroll
    for (int i = 0; i < 4; ++i)
        tile[ty + i * 8][tx] = src[(size_t)(r0 + ty + i * 8) * C + c0 + tx];
    __syncthreads();
    #pragma unroll
    for (int i = 0; i < 4; ++i)
        dst[(size_t)(c0 + ty + i * 8) * R + r0 + tx] = f2bf(tile[tx][ty + i * 8]);
}

// ======== MFMA GEMM: 128x128 tile, BK=64, dbuf, XOR-swizzle, 8 waves/block ========
__global__ __launch_bounds__(512) void gemm_lds(
    const ushort_t* __restrict__ A,  int lda,
    const ushort_t* __restrict__ Bt, int ldb,
    int K,
    float* __restrict__ Cf, ushort_t* __restrict__ Cb, int ldc)
{
    __shared__ ushort_t As[2][128 * 64];
    __shared__ ushort_t Bs[2][128 * 64];

    const int tid  = threadIdx.x;
    const int m0   = blockIdx.y * 128;
    const int n0   = blockIdx.x * 128;
    const int wid  = tid >> 6;          // 0..7
    const int lane = tid & 63;
    const int wm   = (wid >> 2) * 64;
    const int wn   = (wid & 3) * 32;
    const int lr   = lane & 15;

    int rq[2], gq[2], lo[2];
    #pragma unroll
    for (int q = 0; q < 2; ++q) {
        int c = q * 512 + tid;
        rq[q] = c >> 3;
        gq[q] = ((c & 7) ^ (rq[q] & 7)) * 8;
        lo[q] = (q * 512 + wid * 64) * 8;
    }

    f32x4 acc[4][2];
    #pragma unroll
    for (int m = 0; m < 4; ++m)
        #pragma unroll
        for (int n = 0; n < 2; ++n)
            acc[m][n] = (f32x4){0.f, 0.f, 0.f, 0.f};

    const int nk = K >> 6;

    #pragma unroll
    for (int q = 0; q < 2; ++q) {
        gload_lds16(A  + (size_t)(m0 + rq[q]) * lda + gq[q], &As[0][lo[q]]);
        gload_lds16(Bt + (size_t)(n0 + rq[q]) * ldb + gq[q], &Bs[0][lo[q]]);
    }

    for (int k = 0; k < nk; ++k) {
        const int cur = k & 1;
        if (k + 1 < nk) {
            const int k0 = (k + 1) << 6;
            #pragma unroll
            for (int q = 0; q < 2; ++q) {
                gload_lds16(A  + (size_t)(m0 + rq[q]) * lda + k0 + gq[q], &As[cur ^ 1][lo[q]]);
                gload_lds16(Bt + (size_t)(n0 + rq[q]) * ldb + k0 + gq[q], &Bs[cur ^ 1][lo[q]]);
            }
            asm volatile("s_waitcnt vmcnt(4)" ::: "memory");
        } else {
            asm volatile("s_waitcnt vmcnt(0)" ::: "memory");
        }
        __builtin_amdgcn_sched_barrier(0);
        __builtin_amdgcn_s_barrier();

        #pragma unroll
        for (int kk = 0; kk < 2; ++kk) {
            const int lg = (lane >> 4) + kk * 4;
            const int pc = (lg ^ (lr & 7)) * 8;
            bf16x8 af[4], bfr[2];
            #pragma unroll
            for (int m = 0; m < 4; ++m)
                af[m] = *(const bf16x8*)(&As[cur][(wm + m * 16 + lr) * 64 + pc]);
            #pragma unroll
            for (int n = 0; n < 2; ++n)
                bfr[n] = *(const bf16x8*)(&Bs[cur][(wn + n * 16 + lr) * 64 + pc]);
            #pragma unroll
            for (int m = 0; m < 4; ++m)
                #pragma unroll
                for (int n = 0; n < 2; ++n)
                    acc[m][n] = __builtin_amdgcn_mfma_f32_16x16x32_bf16(af[m], bfr[n], acc[m][n], 0, 0, 0);
        }
        __builtin_amdgcn_s_barrier();
    }

    const int rbase = (lane >> 4) * 4;
    #pragma unroll
    for (int m = 0; m < 4; ++m) {
        #pragma unroll
        for (int n = 0; n < 2; ++n) {
            int col = n0 + wn + n * 16 + lr;
            #pragma unroll
            for (int r = 0; r < 4; ++r) {
                int row = m0 + wm + m * 16 + rbase + r;
                float v = acc[m][n][r];
                if (Cf) Cf[(size_t)row * ldc + col] = v;
                if (Cb) Cb[(size_t)row * ldc + col] = f2bf(v);
            }
        }
    }
}

// ======== G4 split-K variant, same 8-wave 128x128 pipeline ========
__global__ __launch_bounds__(512) void gemm_lds_sk(
    const ushort_t* __restrict__ A,  int lda,
    const ushort_t* __restrict__ Bt, int ldb,
    int klen,
    float* __restrict__ Part, int ldc, int mn)   // Part[z][M][ldc]
{
    __shared__ ushort_t As[2][128 * 64];
    __shared__ ushort_t Bs[2][128 * 64];

    const int tid  = threadIdx.x;
    const int m0   = blockIdx.y * 128;
    const int n0   = blockIdx.x * 128;
    const int kb   = blockIdx.z * klen;
    float* Cf = Part + (size_t)blockIdx.z * mn;

    const int wid  = tid >> 6;
    const int lane = tid & 63;
    const int wm   = (wid >> 2) * 64;
    const int wn   = (wid & 3) * 32;
    const int lr   = lane & 15;

    int rq[2], gq[2], lo[2];
    #pragma unroll
    for (int q = 0; q < 2; ++q) {
        int c = q * 512 + tid;
        rq[q] = c >> 3;
        gq[q] = ((c & 7) ^ (rq[q] & 7)) * 8;
        lo[q] = (q * 512 + wid * 64) * 8;
    }

    f32x4 acc[4][2];
    #pragma unroll
    for (int m = 0; m < 4; ++m)
        #pragma unroll
        for (int n = 0; n < 2; ++n)
            acc[m][n] = (f32x4){0.f, 0.f, 0.f, 0.f};

    const int nk = klen >> 6;

    #pragma unroll
    for (int q = 0; q < 2; ++q) {
        gload_lds16(A  + (size_t)(m0 + rq[q]) * lda + kb + gq[q], &As[0][lo[q]]);
        gload_lds16(Bt + (size_t)(n0 + rq[q]) * ldb + kb + gq[q], &Bs[0][lo[q]]);
    }

    for (int k = 0; k < nk; ++k) {
        const int cur = k & 1;
        if (k + 1 < nk) {
            const int k0 = kb + ((k + 1) << 6);
            #pragma unroll
            for (int q = 0; q < 2; ++q) {
                gload_lds16(A  + (size_t)(m0 + rq[q]) * lda + k0 + gq[q], &As[cur ^ 1][lo[q]]);
                gload_lds16(Bt + (size_t)(n0 + rq[q]) * ldb + k0 + gq[q], &Bs[cur ^ 1][lo[q]]);
            }
            asm volatile("s_waitcnt vmcnt(4)" ::: "memory");
        } else {
            asm volatile("s_waitcnt vmcnt(0)" ::: "memory");
        }
        __builtin_amdgcn_sched_barrier(0);
        __builtin_amdgcn_s_barrier();

        #pragma unroll
        for (int kk = 0; kk < 2; ++kk) {
            const int lg = (lane >> 4) + kk * 4;
            const int pc = (lg ^ (lr & 7)) * 8;
            bf16x8 af[4], bfr[2];
            #pragma unroll
            for (int m = 0; m < 4; ++m)
                af[m] = *(const bf16x8*)(&As[cur][(wm + m * 16 + lr) * 64 + pc]);
            #pragma unroll
            for (int n = 0; n < 2; ++n)
                bfr[n] = *(const bf16x8*)(&Bs[cur][(wn + n * 16 + lr) * 64 + pc]);
            #pragma unroll
            for (int m = 0; m < 4; ++m)
                #pragma unroll
                for (int n = 0; n < 2; ++n)
                    acc[m][n] = __builtin_amdgcn_mfma_f32_16x16x32_bf16(af[m], bfr[n], acc[m][n], 0, 0, 0);
        }
        __builtin_amdgcn_s_barrier();
    }

    const int rbase = (lane >> 4) * 4;
    #pragma unroll
    for (int m = 0; m < 4; ++m) {
        #pragma unroll
        for (int n = 0; n < 2; ++n) {
            int col = n0 + wn + n * 16 + lr;
            #pragma unroll
            for (int r = 0; r < 4; ++r) {
                int row = m0 + wm + m * 16 + rbase + r;
                Cf[(size_t)row * ldc + col] = acc[m][n][r];
            }
        }
    }
}

// sum G4SK partials -> f32 out
__global__ __launch_bounds__(256) void g4_reduce(
    const float* __restrict__ Part, float* __restrict__ out)
{
    int i = (blockIdx.x * 256 + threadIdx.x) * 4;
    const size_t mn = (size_t)BL * DIM;
    f32x4 s = *(const f32x4*)(Part + i);
    #pragma unroll
    for (int z = 1; z < G4SK; ++z)
        s += *(const f32x4*)(Part + z * mn + i);
    *(f32x4*)(out + i) = s;
}

// ======== G2 split-K ========
__global__ __launch_bounds__(256) void gemm_n96_splitk(
    const ushort_t* __restrict__ A,
    const ushort_t* __restrict__ Bt,
    float* __restrict__ Ppart)
{
    __shared__ ushort_t As[128 * 40];
    __shared__ ushort_t Bs[96 * 40];

    const int tid   = threadIdx.x;
    const int ks    = blockIdx.x;
    const int m0    = blockIdx.y * 128;
    const int kbase = ks * (DINNER / KSLICE);
    const int wid   = tid >> 6;
    const int lane  = tid & 63;
    const int wm    = wid * 32;
    const int lr    = lane & 15;
    const int lk    = (lane >> 4) * 8;

    f32x4 acc[2][6];
    #pragma unroll
    for (int m = 0; m < 2; ++m)
        #pragma unroll
        for (int n = 0; n < 6; ++n)
            acc[m][n] = (f32x4){0.f, 0.f, 0.f, 0.f};

    for (int k0 = kbase; k0 < kbase + DINNER / KSLICE; k0 += 32) {
        #pragma unroll
        for (int c = 0; c < 2; ++c) {
            int cid = tid + c * 256;
            int row = cid >> 2, ck = (cid & 3) * 8;
            *(uint4*)(&As[row * 40 + ck]) =
                *(const uint4*)(A + (size_t)(m0 + row) * DINNER + k0 + ck);
        }
        {
            int row = tid >> 2, ck = (tid & 3) * 8;
            *(uint4*)(&Bs[row * 40 + ck]) =
                *(const uint4*)(Bt + (size_t)row * DINNER + k0 + ck);
            if (tid < 128) {
                int cid = 256 + tid;
                int row2 = cid >> 2, ck2 = (cid & 3) * 8;
                *(uint4*)(&Bs[row2 * 40 + ck2]) =
                    *(const uint4*)(Bt + (size_t)row2 * DINNER + k0 + ck2);
            }
        }
        __syncthreads();

        bf16x8 af[2], bfr[6];
        #pragma unroll
        for (int m = 0; m < 2; ++m)
            af[m] = *(const bf16x8*)(&As[(wm + m * 16 + lr) * 40 + lk]);
        #pragma unroll
        for (int n = 0; n < 6; ++n)
            bfr[n] = *(const bf16x8*)(&Bs[(n * 16 + lr) * 40 + lk]);

        #pragma unroll
        for (int m = 0; m < 2; ++m)
            #pragma unroll
            for (int n = 0; n < 6; ++n)
                acc[m][n] = __builtin_amdgcn_mfma_f32_16x16x32_bf16(af[m], bfr[n], acc[m][n], 0, 0, 0);
        __syncthreads();
    }

    const int rbase = (lane >> 4) * 4;
    #pragma unroll
    for (int m = 0; m < 2; ++m) {
        #pragma unroll
        for (int n = 0; n < 6; ++n) {
            int col = n * 16 + lr;
            #pragma unroll
            for (int r = 0; r < 4; ++r) {
                int row = m0 + wm + m * 16 + rbase + r;
                Ppart[((size_t)ks * BL + row) * XDBLW + col] = acc[m][n][r];
            }
        }
    }
}

// reduce split-K partials -> xdbl
__global__ __launch_bounds__(256) void g2_reduce(
    const float* __restrict__ Ppart, float* __restrict__ xdbl)
{
    int idx = blockIdx.x * 256 + threadIdx.x;
    int row = idx / 24, cg = (idx % 24) * 4;
    f32x4 s = (f32x4){0.f, 0.f, 0.f, 0.f};
    #pragma unroll
    for (int ks = 0; ks < KSLICE; ++ks)
        s += *(const f32x4*)(Ppart + ((size_t)ks * BL + row) * XDBLW + cg);
    *(f32x4*)(xdbl + (size_t)row * XDBLW + cg) = s;
}

// ======== scan_p1f: fused delta (dt_proj+softplus) + chunk-scan phase 1 ========
// grid: 8 d-slices x (BATCH*NCHUNK) row-chunks = 512 blocks. Same blocking as the
// old delta_v6 AND scan_p1 (32 rows x 256 d). LDS 40 KB -> 4 blocks/CU:
//   [0,32K):  WSb bf16[64][256] (phase A)  OVERLAID WITH  dlS f32[32][256] (phase B)
//   [32K,40K): dS f32[32][64]  (dlt rows)
__global__ __launch_bounds__(256, 4) void scan_p1f(
    const float* __restrict__ xdbl,     // BL x 96 (dlt cols 0..64, B at +64)
    const float* __restrict__ Wdt,      // 64 x 2048 f32
    const float* __restrict__ dtb,      // 2048
    const ushort_t* __restrict__ hb,    // BL x 2048 bf16
    const float* __restrict__ Alog,     // 2048 x 16
    ushort_t* __restrict__ delta_bf,    // BL x 2048 bf16 (out, for scan_p3)
    float* __restrict__ Pbuf,
    float* __restrict__ Sbuf)
{
    __shared__ __align__(16) char smem[40960];
    ushort_t (*WSb)[256] = (ushort_t(*)[256])smem;          // 64x256 bf16, 32 KB
    float    (*dlS)[256] = (float(*)[256])smem;             // 32x256 f32, 32 KB (overlay)
    float    (*dS)[64]   = (float(*)[64])(smem + 32768);    // 32x64 f32, 8 KB

    const int tid = threadIdx.x;
    const int d0  = (blockIdx.x & 7) * 256;
    const int bc  = blockIdx.x >> 3;
    const int b   = bc >> 5;
    const int c   = bc & (NCHUNK - 1);
    const int t0  = c * TCHUNK;
    const size_t row0 = (size_t)(b * SEQ + t0);

    // ---- phase A staging: W (f32 -> bf16) + dlt rows ----
    #pragma unroll
    for (int i = 0; i < 16; ++i) {
        int cc = i * 256 + tid;
        int k = cc >> 6, co = (cc & 63) * 4;
        f32x4 v = *(const f32x4*)(Wdt + (size_t)k * DINNER + d0 + co);
        ushort_t b0 = f2bf(v[0]), b1 = f2bf(v[1]), b2 = f2bf(v[2]), b3 = f2bf(v[3]);
        *(uint2*)&WSb[k][co] = make_uint2((unsigned)b0 | ((unsigned)b1 << 16),
                                          (unsigned)b2 | ((unsigned)b3 << 16));
    }
    #pragma unroll
    for (int i = 0; i < 2; ++i) {
        int cc = i * 256 + tid;
        int r = cc >> 4, co = (cc & 15) * 4;
        *(f32x4*)&dS[r][co] = *(const f32x4*)(xdbl + (row0 + r) * XDBLW + co);
    }
    __syncthreads();

    // ---- phase A dot: thread = 4 consecutive d x 8 rows (delta_v6 layout) ----
    const int w    = tid >> 6;
    const int lane = tid & 63;
    const int dd   = lane * 4;

    f32x4 acc[8];
    {
        f32x4 bb = *(const f32x4*)(dtb + d0 + dd);
        #pragma unroll
        for (int r = 0; r < 8; ++r) acc[r] = bb;
    }
    for (int kq = 0; kq < 16; ++kq) {
        f32x4 dv[8];
        #pragma unroll
        for (int r = 0; r < 8; ++r)
            dv[r] = *(const f32x4*)&dS[w * 8 + r][kq * 4];   // wave-uniform broadcast
        #pragma unroll
        for (int kk = 0; kk < 4; ++kk) {
            uint2 wp = *(const uint2*)&WSb[kq * 4 + kk][dd];
            float w0, w1, w2, w3;
            unpack_bf2(wp.x, w0, w1);
            unpack_bf2(wp.y, w2, w3);
            #pragma unroll
            for (int r = 0; r < 8; ++r) {
                float dk = dv[r][kk];
                acc[r][0] = fmaf(dk, w0, acc[r][0]);
                acc[r][1] = fmaf(dk, w1, acc[r][1]);
                acc[r][2] = fmaf(dk, w2, acc[r][2]);
                acc[r][3] = fmaf(dk, w3, acc[r][3]);
            }
        }
    }

    // softplus + bf16 round; write global dltbf (for p3); keep rounded values
    float rr[8][4];
    #pragma unroll
    for (int r = 0; r < 8; ++r) {
        ushort_t o[4];
        #pragma unroll
        for (int j = 0; j < 4; ++j) {
            float sp = softplus_fast(acc[r][j]);
            o[j] = f2bf(sp);
            rr[r][j] = bf2f(o[j]);       // p1 uses the SAME rounded dl as p3
        }
        const size_t rowb = (row0 + w * 8 + r) * DINNER + d0;
        *(uint2*)(delta_bf + rowb + dd) = make_uint2(
            (unsigned)o[0] | ((unsigned)o[1] << 16), (unsigned)o[2] | ((unsigned)o[3] << 16));
    }

    __syncthreads();   // all WSb reads done -> safe to overlay
    #pragma unroll
    for (int r = 0; r < 8; ++r)
        *(f32x4*)&dlS[w * 8 + r][dd] = (f32x4){rr[r][0], rr[r][1], rr[r][2], rr[r][3]};
    __syncthreads();

    // ---- phase B: chunk-scan (old scan_p1 body; dl from LDS) ----
    const int d = d0 + tid;

    float A[NSTATE];
    #pragma unroll
    for (int q = 0; q < 4; ++q) {
        f32x4 al = *(const f32x4*)(Alog + (size_t)d * NSTATE + q * 4);
        #pragma unroll
        for (int j = 0; j < 4; ++j)
            A[q * 4 + j] = -hexp2(al[j] * LOG2E) * LOG2E;
    }

    float s[NSTATE], pp[NSTATE];
    #pragma unroll
    for (int n = 0; n < NSTATE; ++n) { s[n] = 0.f; pp[n] = 1.f; }

    for (int tt = 0; tt < TCHUNK; ++tt) {
        const size_t row = row0 + tt;
        float dl = dlS[tt][tid];
        float hv = bf2f(hb[row * DINNER + d]);
        float dlh = dl * hv;
        float Bv[NSTATE];
        #pragma unroll
        for (int q = 0; q < 4; ++q) {
            f32x4 bv = *(const f32x4*)(xdbl + row * XDBLW + DTRANK + q * 4);
            #pragma unroll
            for (int j = 0; j < 4; ++j) Bv[q * 4 + j] = bv[j];
        }
        #pragma unroll
        for (int n = 0; n < NSTATE; ++n) {
            float a = hexp2(dl * A[n]);
            s[n]  = fmaf(a, s[n], dlh * Bv[n]);
            pp[n] *= a;
        }
    }

    const size_t o = (((size_t)b * NCHUNK + c) * DINNER + d) * NSTATE;
    #pragma unroll
    for (int q = 0; q < 4; ++q) {
        *(f32x4*)(Sbuf + o + q * 4) = (f32x4){s[q*4+0], s[q*4+1], s[q*4+2], s[q*4+3]};
        *(f32x4*)(Pbuf + o + q * 4) = (f32x4){pp[q*4+0], pp[q*4+1], pp[q*4+2], pp[q*4+3]};
    }
}

// ---------------- conv(4) + bias + SiLU, vectorized (8 d per thread) ----------------
__global__ __launch_bounds__(256) void conv_silu(
    const ushort_t* __restrict__ xrb,   // BL x 4096 bf16 (xp = cols [0,2048))
    const float* __restrict__ convw,
    const float* __restrict__ convb,
    ushort_t* __restrict__ hb)          // BL x 2048 bf16
{
    const int bt = blockIdx.x;
    const int t  = bt & (SEQ - 1);
    const int d0 = threadIdx.x * 8;

    bf16x8 xv[DCONV];
    #pragma unroll
    for (int j = 0; j < DCONV; ++j) {
        int tt = t + j - (DCONV - 1);
        if (tt >= 0)
            xv[j] = *(const bf16x8*)(xrb + (size_t)(bt + j - (DCONV - 1)) * 4096 + d0);
        else
            xv[j] = (bf16x8){0,0,0,0,0,0,0,0};
    }

    ushort_t o[8];
    #pragma unroll
    for (int dd = 0; dd < 8; ++dd) {
        f32x4 w = *(const f32x4*)(convw + (size_t)(d0 + dd) * DCONV);
        float acc = convb[d0 + dd];
        #pragma unroll
        for (int j = 0; j < DCONV; ++j)
            acc = fmaf(w[j], bf2f((ushort_t)xv[j][dd]), acc);
        o[dd] = f2bf(acc * sigmoid_fast(acc));
    }
    uint4 pk;
    pk.x = (unsigned)o[0] | ((unsigned)o[1] << 16);
    pk.y = (unsigned)o[2] | ((unsigned)o[3] << 16);
    pk.z = (unsigned)o[4] | ((unsigned)o[5] << 16);
    pk.w = (unsigned)o[6] | ((unsigned)o[7] << 16);
    *(uint4*)(hb + (size_t)bt * DINNER + d0) = pk;
}

// register-batched carry: load all chunk summaries (independent), chain in-reg, store
__global__ __launch_bounds__(256) void scan_p2(
    const float* __restrict__ Pbuf, float* __restrict__ Sbuf)
{
    const int tid = blockIdx.x * 256 + threadIdx.x;
    const int n = tid & 15;
    const int d = (tid >> 4) & (DINNER - 1);
    const int b = tid >> 15;
    const size_t stride = (size_t)DINNER * NSTATE;
    const size_t base = ((size_t)b * NCHUNK * DINNER + d) * NSTATE + n;

    float S[NCHUNK], P[NCHUNK];
    #pragma unroll
    for (int c = 0; c < NCHUNK; ++c) {
        S[c] = Sbuf[base + c * stride];
        P[c] = Pbuf[base + c * stride];
    }
    float cin = 0.f;
    float O[NCHUNK];
    #pragma unroll
    for (int c = 0; c < NCHUNK; ++c) {
        O[c] = cin;
        cin = fmaf(P[c], cin, S[c]);
    }
    #pragma unroll
    for (int c = 0; c < NCHUNK; ++c)
        Sbuf[base + c * stride] = O[c];
}

__global__ __launch_bounds__(256) void scan_p3(
    const ushort_t* __restrict__ delta_bf,
    const ushort_t* __restrict__ hb,
    const float* __restrict__ xdbl,
    const ushort_t* __restrict__ xrb,
    const float* __restrict__ Alog,
    const float* __restrict__ Dp,
    const float* __restrict__ Sbuf,
    ushort_t* __restrict__ yb)
{
    const int d  = (blockIdx.x & 7) * 256 + threadIdx.x;
    const int bc = blockIdx.x >> 3;
    const int b  = bc >> 5;
    const int c  = bc & (NCHUNK - 1);
    const int t0 = c * TCHUNK;

    float A[NSTATE];
    #pragma unroll
    for (int q = 0; q < 4; ++q) {
        f32x4 al = *(const f32x4*)(Alog + (size_t)d * NSTATE + q * 4);
        #pragma unroll
        for (int j = 0; j < 4; ++j)
            A[q * 4 + j] = -hexp2(al[j] * LOG2E) * LOG2E;
    }
    const float Dd = Dp[d];

    float s[NSTATE];
    const size_t o = (((size_t)b * NCHUNK + c) * DINNER + d) * NSTATE;
    #pragma unroll
    for (int q = 0; q < 4; ++q) {
        f32x4 sv = *(const f32x4*)(Sbuf + o + q * 4);
        #pragma unroll
        for (int j = 0; j < 4; ++j) s[q * 4 + j] = sv[j];
    }

    for (int tt = 0; tt < TCHUNK; ++tt) {
        const size_t row = (size_t)(b * SEQ + t0 + tt);
        float dl = bf2f(delta_bf[row * DINNER + d]);
        float hv = bf2f(hb[row * DINNER + d]);
        float rv = bf2f(xrb[row * 4096 + DINNER + d]);
        float dlh = dl * hv;
        float Bv[NSTATE], Cv[NSTATE];
        #pragma unroll
        for (int q = 0; q < 4; ++q) {
            f32x4 bv = *(const f32x4*)(xdbl + row * XDBLW + DTRANK + q * 4);
            f32x4 cv = *(const f32x4*)(xdbl + row * XDBLW + DTRANK + NSTATE + q * 4);
            #pragma unroll
            for (int j = 0; j < 4; ++j) { Bv[q*4+j] = bv[j]; Cv[q*4+j] = cv[j]; }
        }
        float y = 0.f;
        #pragma unroll
        for (int n = 0; n < NSTATE; ++n) {
            float a = hexp2(dl * A[n]);
            s[n] = fmaf(a, s[n], dlh * Bv[n]);
            y = fmaf(s[n], Cv[n], y);
        }
        y = fmaf(hv, Dd, y);
        y = y * rv * sigmoid_fast(rv);
        yb[row * DINNER + d] = f2bf(y);
    }
}

extern "C" void kernel_launch(void* const* d_in, const int* in_sizes, int n_in,
                              void* d_out, int out_size, void* d_ws, size_t ws_size,
                              hipStream_t stream)
{
    const float* x     = (const float*)d_in[0];
    const float* Win   = (const float*)d_in[1];
    const float* convw = (const float*)d_in[2];
    const float* convb = (const float*)d_in[3];
    const float* Wxp   = (const float*)d_in[4];
    const float* Wdt   = (const float*)d_in[5];
    const float* dtb   = (const float*)d_in[6];
    const float* Alog  = (const float*)d_in[7];
    const float* Dp    = (const float*)d_in[8];
    const float* Wout  = (const float*)d_in[9];
    float* out = (float*)d_out;

    char* base = (char*)d_ws; size_t off = 0;
    auto alloc = [&](size_t bytes) -> char* {
        char* q = base + off;
        off = (off + bytes + 255) & ~(size_t)255;
        return q;
    };
    ushort_t* WtIn   = (ushort_t*)alloc((size_t)4096 * 1024 * 2);
    ushort_t* WtOut  = (ushort_t*)alloc((size_t)1024 * 2048 * 2);
    ushort_t* WtXp   = (ushort_t*)alloc((size_t)96   * 2048 * 2);
    ushort_t* xb     = (ushort_t*)alloc((size_t)BL * DIM * 2);
    ushort_t* xrb    = (ushort_t*)alloc((size_t)BL * 4096 * 2);
    ushort_t* hb     = (ushort_t*)alloc((size_t)BL * DINNER * 2);
    float*    xdbl   = (float*)   alloc((size_t)BL * XDBLW * 4);
    ushort_t* dltbf  = (ushort_t*)alloc((size_t)BL * DINNER * 2);
    ushort_t* yb     = (ushort_t*)alloc((size_t)BL * DINNER * 2);
    float*    Pbuf   = (float*)   alloc((size_t)BATCH * NCHUNK * DINNER * NSTATE * 4);
    float*    Sbuf   = (float*)   alloc((size_t)BATCH * NCHUNK * DINNER * NSTATE * 4);
    float*    Ppart  = (float*)   alloc((size_t)KSLICE * BL * XDBLW * 4);
    float*    G4part = (float*)   alloc((size_t)G4SK * BL * DIM * 4);   // 32 MB
    (void)ws_size;

    prep_fused<<<dim3(8384), 256, 0, stream>>>(Win, WtIn, Wout, WtOut, Wxp, WtXp, x, xb);

    // G1: xr = x @ in_proj_w (2048 x 4096, K=1024) -> bf16; 128x128, 8 waves/block
    gemm_lds<<<dim3(4096/128, BL/128), 512, 0, stream>>>(
        xb, DIM, WtIn, DIM, DIM, nullptr, xrb, 2*DINNER);

    conv_silu<<<dim3(BL), 256, 0, stream>>>(xrb, convw, convb, hb);

    gemm_n96_splitk<<<dim3(KSLICE, BL/128), 256, 0, stream>>>(hb, WtXp, Ppart);
    g2_reduce<<<dim3(BL * 24 / 256), 256, 0, stream>>>(Ppart, xdbl);

    // fused delta + scan phase 1 (replaces delta_v6 + scan_p1)
    scan_p1f<<<dim3(8 * BATCH * NCHUNK), 256, 0, stream>>>(
        xdbl, Wdt, dtb, hb, Alog, dltbf, Pbuf, Sbuf);

    scan_p2<<<dim3(BATCH * DINNER * NSTATE / 256), 256, 0, stream>>>(Pbuf, Sbuf);
    scan_p3<<<dim3(8 * BATCH * NCHUNK), 256, 0, stream>>>(dltbf, hb, xdbl, xrb, Alog, Dp, Sbuf, yb);

    // G4: out = y @ out_proj_w (2048 x 1024, K=2048) via split-K=4; 8 waves/block
    gemm_lds_sk<<<dim3(DIM/128, BL/128, G4SK), 512, 0, stream>>>(
        yb, DINNER, WtOut, DINNER, DINNER/G4SK, G4part, DIM, BL*DIM);
    g4_reduce<<<dim3(BL*DIM/4/256), 256, 0, stream>>>(G4part, out);
}